// Round 13
// baseline (1124.974 us; speedup 1.0000x reference)
//
#include <hip/hip_runtime.h>
#include <math.h>

#define NB 8
#define NN 10000
#define NT 12
#define ND 16
#define NH 128
#define NE 160000
#define BN (NB * NN)  // 80000

typedef __attribute__((ext_vector_type(8))) short short8v;
typedef __attribute__((ext_vector_type(4))) float f32x4;
typedef unsigned short u16;

#define NL2E  -1.442695041f   // -log2(e)
#define N2L2E -2.885390082f   // -2*log2(e)

__device__ __forceinline__ u16 bf16_rn(float f) {
    unsigned int u = __float_as_uint(f);
    u += 0x7fffu + ((u >> 16) & 1u);
    return (u16)(u >> 16);
}
__device__ __forceinline__ float bf16f(u16 s) {
    return __uint_as_float((unsigned int)s << 16);
}
// trunc-hi + rn-lo split packed as (lo<<16)|hi  (x staging keeps hi/lo)
__device__ __forceinline__ unsigned int pack_split(float f) {
    unsigned int u = __float_as_uint(f);
    unsigned int hh = u >> 16;
    float rem = f - __uint_as_float(u & 0xffff0000u);
    unsigned int hl = bf16_rn(rem);
    return (hl << 16) | hh;
}

// ---------- prep: scaled bf16 weights (exp2 gates) + CSR init ---------------
__global__ void prep_w_k(const float* __restrict__ Whh, const float* __restrict__ Wih,
                         const float* __restrict__ g1w, const float* __restrict__ g2w,
                         u16* __restrict__ whh_hi, u16* __restrict__ wih_hi2,
                         u16* __restrict__ g1hi, u16* __restrict__ g2hi,
                         float* __restrict__ deg, int* __restrict__ cnt, int* __restrict__ fill)
{
    int i = blockIdx.x * 256 + threadIdx.x;   // 65536 threads
    if (i < 512 * 128) {
        int j = i >> 7;
        float s = ((j >> 7) == 2) ? N2L2E : NL2E;
        whh_hi[i] = bf16_rn(s * Whh[i]);
    }
    if (i < 512 * 16) {
        int row = i >> 4, d = i & 15;
        float s = ((row >> 7) == 2) ? N2L2E : NL2E;
        u16 h = bf16_rn(s * Wih[i]);
        wih_hi2[row * 32 + d] = h;        // duplicated: pairs with [x_hi; x_lo]
        wih_hi2[row * 32 + 16 + d] = h;
    }
    if (i < 128 * 128) {
        g1hi[i] = bf16_rn(g1w[i]);
        g2hi[i] = bf16_rn(g2w[i]);
    }
    if (i < NN) { deg[i] = 1.0f; cnt[i] = 0; fill[i] = 0; }   // 1.0 = self-loop
}

// ---------- LSTM v4e: lstm4d at 4 waves/SIMD (2 blocks/CU, decoupled) -------
// Demand measured 84 VGPR at (512,2) -> fits the 128 cap of (512,4) with
// headroom; 2 co-resident blocks give independent barrier domains so one
// block's trans-heavy epilogue overlaps the other's MFMA phase.
__global__ __launch_bounds__(512, 4) void lstm4e_k(
    const float* __restrict__ x,
    const u16* __restrict__ whh_hi, const u16* __restrict__ wih_hi2,
    const float* __restrict__ bih, const float* __restrict__ bhh,
    u16* __restrict__ hhi_g)
{
    __shared__ __align__(16) u16 Hhi[2][64][128];   // 32 KB (double-buffered)
    __shared__ __align__(16) u16 Hx[2][64][40];     // 10 KB (80B rows)
    const int tid = threadIdx.x;
    const int lane = tid & 63;
    const int wid = tid >> 6;
    const int j0 = wid * 16;
    const int l15 = lane & 15;
    const int lg = lane >> 4;          // 0..3
    const long seq0 = (long)blockIdx.x * 64;
    const int swzr = (l15 & 7) << 3;   // read-side XOR swizzle
    const int xs_seq = tid >> 3;       // x staging: 8 threads/seq-row
    const int xd0 = (tid & 7) * 2;

    // B fragments in registers: Whh (scaled bf16, 64 VGPR) + Wih (16 VGPR)
    short8v Bh[4][4];                  // [kt][gate]
    short8v b1[4];
    float bv[4];
#pragma unroll
    for (int kt = 0; kt < 4; ++kt)
#pragma unroll
        for (int g = 0; g < 4; ++g) {
            int row = g * NH + j0 + l15;
            Bh[kt][g] = *(const short8v*)(whh_hi + row * NH + kt * 32 + 8 * lg);
        }
#pragma unroll
    for (int g = 0; g < 4; ++g) {
        int row = g * NH + j0 + l15;
        b1[g] = *(const short8v*)(wih_hi2 + row * 32 + 8 * lg);
        bv[g] = (bih[row] + bhh[row]) * ((g == 2) ? N2L2E : NL2E);
    }

    // stage x for t=0 ([x_hi ; x_lo] halves)
    {
        float2 xv = *(const float2*)(x + ((seq0 + xs_seq) * NT + 0) * ND + xd0);
        unsigned int p0 = pack_split(xv.x), p1 = pack_split(xv.y);
        *(ushort2*)&Hx[0][xs_seq][xd0] = make_ushort2((u16)p0, (u16)p1);
        *(ushort2*)&Hx[0][xs_seq][16 + xd0] = make_ushort2((u16)(p0 >> 16), (u16)(p1 >> 16));
    }
    f32x4 c[4];
#pragma unroll
    for (int m = 0; m < 4; ++m) c[m] = (f32x4){0.f, 0.f, 0.f, 0.f};
    __syncthreads();

    for (int t = 0; t < NT; ++t) {
        const int cur = t & 1, nxt = cur ^ 1;
        float2 xv;
        if (t + 1 < NT)
            xv = *(const float2*)(x + ((seq0 + xs_seq) * NT + (t + 1)) * ND + xd0);

#pragma unroll
        for (int m = 0; m < 4; ++m) {
            const int sq = m * 16 + l15;
            short8v xa = *(const short8v*)&Hx[cur][sq][8 * lg];

            f32x4 acc[4];
#pragma unroll
            for (int g = 0; g < 4; ++g)
                acc[g] = (f32x4){bv[g], bv[g], bv[g], bv[g]};

            if (t > 0) {
#pragma unroll
                for (int kt = 0; kt < 4; ++kt) {
                    const int kk = (kt * 32 + 8 * lg) ^ swzr;
                    short8v ah = *(const short8v*)&Hhi[cur][sq][kk];
#pragma unroll
                    for (int g = 0; g < 4; ++g)
                        acc[g] = __builtin_amdgcn_mfma_f32_16x16x32_bf16(ah, Bh[kt][g], acc[g], 0, 0, 0);
                }
            }
#pragma unroll
            for (int g = 0; g < 4; ++g)
                acc[g] = __builtin_amdgcn_mfma_f32_16x16x32_bf16(xa, b1[g], acc[g], 0, 0, 0);

            // epilogue: 5 exp2 + 3 paired rcp per element (pre-scaled gates)
#pragma unroll
            for (int r = 0; r < 4; ++r) {
                const float ui = exp2f(acc[0][r]);
                const float uf = exp2f(acc[1][r]);
                const float ug = exp2f(acc[2][r]);
                const float uo = exp2f(acc[3][r]);
                const float di = 1.f + ui, df = 1.f + uf;
                const float dg = 1.f + ug, dd = 1.f + uo;
                const float r0 = __builtin_amdgcn_rcpf(di * df);
                const float r1 = __builtin_amdgcn_rcpf(dg * dd);
                const float si = r0 * df;                   // sigmoid(i)
                const float sf = r0 * di;                   // sigmoid(f)
                const float tg = fmaf(2.f, r1 * dd, -1.f);  // tanh(g)
                const float so = r1 * dg;                   // sigmoid(o)
                const float cc = fmaf(sf, c[m][r], si * tg);
                c[m][r] = cc;
                const float uc = exp2f(cc * N2L2E);
                const float rc = __builtin_amdgcn_rcpf(1.f + uc);
                const float hv = fmaf(2.f, so * rc, -so);   // o * tanh(c)
                const int sq2 = m * 16 + 4 * lg + r;
                const int jj = (j0 + l15) ^ ((sq2 & 7) << 3);
                Hhi[nxt][sq2][jj] = bf16_rn(hv);
            }
        }

        if (t + 1 < NT) {
            unsigned int p0 = pack_split(xv.x), p1 = pack_split(xv.y);
            *(ushort2*)&Hx[nxt][xs_seq][xd0] = make_ushort2((u16)p0, (u16)p1);
            *(ushort2*)&Hx[nxt][xs_seq][16 + xd0] = make_ushort2((u16)(p0 >> 16), (u16)(p1 >> 16));
        }
        __syncthreads();
    }

    // copy-out (node-major rows n*8+b): final h in Hhi[0]
    for (int ci = tid; ci < 1024; ci += 512) {
        int s = ci >> 4, g16 = ci & 15;
        int sg = g16 ^ (s & 7);
        unsigned int sglob = (unsigned int)(seq0 + s);
        unsigned int b = sglob / NN;
        unsigned int n = sglob - b * NN;
        uint4 v = *(const uint4*)&Hhi[0][s][sg * 8];
        *(uint4*)(hhi_g + ((long)n * 8 + b) * NH + g16 * 8) = v;
    }
}

// ---------- GCN GEMM: out = A @ W^T, single bf16 A plane, bf16 out ----------
__global__ __launch_bounds__(512) void gemmx4_k(
    const u16* __restrict__ Ah, const u16* __restrict__ Whi,
    u16* __restrict__ out)
{
    const int tid = threadIdx.x;
    const int lane = tid & 63;
    const int wid = tid >> 6;
    const int j0 = wid * 16;
    const int l15 = lane & 15;
    const int lg = lane >> 4;
    const long row0 = (long)blockIdx.x * 64;

    short8v Bh[4];
#pragma unroll
    for (int kt = 0; kt < 4; ++kt)
        Bh[kt] = *(const short8v*)(Whi + (j0 + l15) * NH + kt * 32 + 8 * lg);

#pragma unroll
    for (int m = 0; m < 4; ++m) {
        f32x4 acc = (f32x4){0.f, 0.f, 0.f, 0.f};
#pragma unroll
        for (int kt = 0; kt < 4; ++kt) {
            long ar = (row0 + m * 16 + l15) * NH + kt * 32 + 8 * lg;
            short8v ah = *(const short8v*)(Ah + ar);
            acc = __builtin_amdgcn_mfma_f32_16x16x32_bf16(ah, Bh[kt], acc, 0, 0, 0);
        }
#pragma unroll
        for (int r = 0; r < 4; ++r)
            out[(row0 + m * 16 + 4 * lg + r) * NH + j0 + l15] = bf16_rn(acc[r]);
    }
}

// ---------------- degree accumulation ---------------------------------------
__global__ void degacc_k(const int* __restrict__ ei, const float* __restrict__ ew,
                         float* deg, int* cnt) {
    int e = blockIdx.x * 256 + threadIdx.x;
    if (e < NE) {
        int d = ei[NE + e];
        atomicAdd(&deg[d], ew[e]);
        atomicAdd(&cnt[d], 1);
    }
}

// ---------------- scan (+ dinv) ---------------------------------------------
__global__ __launch_bounds__(1024) void scan_k(const int* __restrict__ cnt,
                                               int* __restrict__ rowp,
                                               const float* __restrict__ deg,
                                               float* __restrict__ dinv) {
    for (int idx = threadIdx.x; idx < NN; idx += 1024) {
        float d = deg[idx];
        dinv[idx] = d > 0.f ? rsqrtf(d) : 0.f;
    }
    __shared__ int sA[1024];
    __shared__ int sB[1024];
    const int tid = threadIdx.x;
    const int CH = 10;
    int base = tid * CH;
    int local[CH];
    int ssum = 0;
#pragma unroll
    for (int i = 0; i < CH; ++i) {
        int idx = base + i;
        int v = (idx < NN) ? cnt[idx] : 0;
        local[i] = v; ssum += v;
    }
    int* src = sA; int* dst = sB;
    src[tid] = ssum;
    __syncthreads();
    for (int off = 1; off < 1024; off <<= 1) {
        int v = src[tid];
        if (tid >= off) v += src[tid - off];
        dst[tid] = v;
        __syncthreads();
        int* tmp = src; src = dst; dst = tmp;
    }
    int run = src[tid] - ssum;
#pragma unroll
    for (int i = 0; i < CH; ++i) {
        int idx = base + i;
        if (idx < NN) rowp[idx] = run;
        run += local[i];
    }
    if (tid == 1023) rowp[NN] = src[1023];
}

__global__ void scatter_k(const int* __restrict__ ei, const float* __restrict__ ew,
                          const float* __restrict__ dinv, const int* __restrict__ rowp,
                          int* fill, int* __restrict__ col, float* __restrict__ val)
{
    int e = blockIdx.x * 256 + threadIdx.x;
    if (e >= NE) return;
    int srcn = ei[e], d = ei[NE + e];
    int pos = rowp[d] + atomicAdd(&fill[d], 1);
    col[pos] = srcn;
    val[pos] = dinv[srcn] * ew[e] * dinv[d];
}

// ---------- gather v6: node-major bf16 rows; EMIT=0 -> bf16, 1 -> fused FC --
template<int EMIT>
__global__ __launch_bounds__(256) void gather6_k(const u16* __restrict__ xlb,
    const int* __restrict__ rowp, const int* __restrict__ col,
    const float* __restrict__ val, const float* __restrict__ dinv,
    const float* __restrict__ bias,
    u16* __restrict__ ohi,
    const float* __restrict__ fcw, const float* __restrict__ fcb,
    float* __restrict__ out)
{
    __shared__ float hrow[8][132];
    __shared__ float wl[16][132];
    const int n = blockIdx.x;
    const int tid = threadIdx.x;
    const int q = tid & 31;            // channel-quad (bias index)
    if (EMIT == 1) {
        for (int l = tid; l < 16 * 128; l += 256)
            wl[l >> 7][l & 127] = fcw[l];
    }
    const float dn = dinv[n];
    const float sn = dn * dn;          // self-loop norm
    float4 acc;
    {
        ushort4 u = *(const ushort4*)(xlb + (long)n * 1024 + tid * 4);
        acc.x = sn * bf16f(u.x); acc.y = sn * bf16f(u.y);
        acc.z = sn * bf16f(u.z); acc.w = sn * bf16f(u.w);
    }
    int e = rowp[n];
    const int e1 = rowp[n + 1];
    for (; e + 2 <= e1; e += 2) {      // edge scalars wave-uniform -> s_load
        const int s0 = col[e], s1 = col[e + 1];
        const float w0 = val[e], w1 = val[e + 1];
        const ushort4 u0 = *(const ushort4*)(xlb + (long)s0 * 1024 + tid * 4);
        const ushort4 u1 = *(const ushort4*)(xlb + (long)s1 * 1024 + tid * 4);
        acc.x = fmaf(w0, bf16f(u0.x), acc.x); acc.y = fmaf(w0, bf16f(u0.y), acc.y);
        acc.z = fmaf(w0, bf16f(u0.z), acc.z); acc.w = fmaf(w0, bf16f(u0.w), acc.w);
        acc.x = fmaf(w1, bf16f(u1.x), acc.x); acc.y = fmaf(w1, bf16f(u1.y), acc.y);
        acc.z = fmaf(w1, bf16f(u1.z), acc.z); acc.w = fmaf(w1, bf16f(u1.w), acc.w);
    }
    if (e < e1) {
        const int s0 = col[e];
        const float w0 = val[e];
        const ushort4 u0 = *(const ushort4*)(xlb + (long)s0 * 1024 + tid * 4);
        acc.x = fmaf(w0, bf16f(u0.x), acc.x); acc.y = fmaf(w0, bf16f(u0.y), acc.y);
        acc.z = fmaf(w0, bf16f(u0.z), acc.z); acc.w = fmaf(w0, bf16f(u0.w), acc.w);
    }
    const float4 bb = ((const float4*)bias)[q];
    const float o0 = fmaxf(acc.x + bb.x, 0.f);
    const float o1 = fmaxf(acc.y + bb.y, 0.f);
    const float o2 = fmaxf(acc.z + bb.z, 0.f);
    const float o3 = fmaxf(acc.w + bb.w, 0.f);
    if (EMIT == 0) {
        ushort4 h4 = make_ushort4(bf16_rn(o0), bf16_rn(o1), bf16_rn(o2), bf16_rn(o3));
        *(ushort4*)(ohi + (long)n * 1024 + tid * 4) = h4;
    } else {
        const int b = tid >> 5;
        *(float4*)&hrow[b][q * 4] = make_float4(o0, o1, o2, o3);
        __syncthreads();
        if (tid < 128) {
            const int b2 = tid >> 4, o = tid & 15;
            float a = fcb[o];
#pragma unroll 8
            for (int k = 0; k < NH; ++k) a = fmaf(hrow[b2][k], wl[o][k], a);
            out[((long)b2 * NN + n) * 16 + o] = a;
        }
    }
}

// ---------------------------------------------------------------------------
extern "C" void kernel_launch(void* const* d_in, const int* in_sizes, int n_in,
                              void* d_out, int out_size, void* d_ws, size_t ws_size,
                              hipStream_t stream)
{
    const float* x   = (const float*)d_in[0];
    const int*   ei  = (const int*)d_in[1];
    const float* ew  = (const float*)d_in[2];
    const float* Wih = (const float*)d_in[3];
    const float* Whh = (const float*)d_in[4];
    const float* bih = (const float*)d_in[5];
    const float* bhh = (const float*)d_in[6];
    const float* g1w = (const float*)d_in[7];
    const float* g1b = (const float*)d_in[8];
    const float* g2w = (const float*)d_in[9];
    const float* g2b = (const float*)d_in[10];
    const float* fcw = (const float*)d_in[11];
    const float* fcb = (const float*)d_in[12];
    float* out = (float*)d_out;

    char* ws = (char*)d_ws;
    u16* whh_hi  = (u16*)(ws + 0);           // 131072
    u16* wih_hi2 = (u16*)(ws + 131072);      // 32768
    u16* g1hi    = (u16*)(ws + 196608);      // 32768
    u16* g2hi    = (u16*)(ws + 229376);      // 32768
    float* deg   = (float*)(ws + 262144);
    float* dinv  = (float*)(ws + 303104);
    int*   cnt   = (int*)(ws + 344064);
    int*   fill  = (int*)(ws + 385024);
    int*   rowp  = (int*)(ws + 425984);
    int*   col   = (int*)(ws + 466176);      // 640000
    float* val   = (float*)(ws + 1106176);   // 640000
    u16* hhi     = (u16*)(ws + 2097152);     // 20480000 (node-major bf16)
    u16* xlb     = (u16*)(ws + 22577152);    // 20480000 (node-major bf16)

    prep_w_k<<<256, 256, 0, stream>>>(Whh, Wih, g1w, g2w, whh_hi, wih_hi2,
                                      g1hi, g2hi, deg, cnt, fill);
    lstm4e_k<<<BN / 64, 512, 0, stream>>>(x, whh_hi, wih_hi2, bih, bhh, hhi);

    degacc_k<<<(NE + 255) / 256, 256, 0, stream>>>(ei, ew, deg, cnt);
    scan_k<<<1, 1024, 0, stream>>>(cnt, rowp, deg, dinv);
    scatter_k<<<(NE + 255) / 256, 256, 0, stream>>>(ei, ew, dinv, rowp, fill, col, val);

    gemmx4_k<<<BN / 64, 512, 0, stream>>>(hhi, g1hi, xlb);
    gather6_k<0><<<NN, 256, 0, stream>>>(xlb, rowp, col, val, dinv, g1b,
                                         hhi, nullptr, nullptr, nullptr);
    gemmx4_k<<<BN / 64, 512, 0, stream>>>(hhi, g2hi, xlb);
    gather6_k<1><<<NN, 256, 0, stream>>>(xlb, rowp, col, val, dinv, g2b,
                                         nullptr, fcw, fcb, out);
}

// Round 14
// 481.612 us; speedup vs baseline: 2.3359x; 2.3359x over previous
//
#include <hip/hip_runtime.h>
#include <math.h>

#define NB 8
#define NN 10000
#define NT 12
#define ND 16
#define NH 128
#define NE 160000
#define BN (NB * NN)  // 80000

typedef __attribute__((ext_vector_type(8))) short short8v;
typedef __attribute__((ext_vector_type(4))) float f32x4;
typedef unsigned short u16;

#define NL2E  -1.442695041f   // -log2(e)
#define N2L2E -2.885390082f   // -2*log2(e)

__device__ __forceinline__ u16 bf16_rn(float f) {
    unsigned int u = __float_as_uint(f);
    u += 0x7fffu + ((u >> 16) & 1u);
    return (u16)(u >> 16);
}
__device__ __forceinline__ float bf16f(u16 s) {
    return __uint_as_float((unsigned int)s << 16);
}
// trunc-hi + rn-lo split packed as (lo<<16)|hi  (x staging keeps hi/lo)
__device__ __forceinline__ unsigned int pack_split(float f) {
    unsigned int u = __float_as_uint(f);
    unsigned int hh = u >> 16;
    float rem = f - __uint_as_float(u & 0xffff0000u);
    unsigned int hl = bf16_rn(rem);
    return (hl << 16) | hh;
}

// ---------- prep: scaled bf16 weights (exp2 gates) + CSR init ---------------
__global__ void prep_w_k(const float* __restrict__ Whh, const float* __restrict__ Wih,
                         const float* __restrict__ g1w, const float* __restrict__ g2w,
                         u16* __restrict__ whh_hi, u16* __restrict__ wih_hi2,
                         u16* __restrict__ g1hi, u16* __restrict__ g2hi,
                         float* __restrict__ deg, int* __restrict__ cnt, int* __restrict__ fill)
{
    int i = blockIdx.x * 256 + threadIdx.x;   // 65536 threads
    if (i < 512 * 128) {
        int j = i >> 7;
        float s = ((j >> 7) == 2) ? N2L2E : NL2E;
        whh_hi[i] = bf16_rn(s * Whh[i]);
    }
    if (i < 512 * 16) {
        int row = i >> 4, d = i & 15;
        float s = ((row >> 7) == 2) ? N2L2E : NL2E;
        u16 h = bf16_rn(s * Wih[i]);
        wih_hi2[row * 32 + d] = h;        // duplicated: pairs with [x_hi; x_lo]
        wih_hi2[row * 32 + 16 + d] = h;
    }
    if (i < 128 * 128) {
        g1hi[i] = bf16_rn(g1w[i]);
        g2hi[i] = bf16_rn(g2w[i]);
    }
    if (i < NN) { deg[i] = 1.0f; cnt[i] = 0; fill[i] = 0; }   // 1.0 = self-loop
}

// ---------- LSTM v4f: round-12 structure, trans-reduced epilogue ------------
// (512,2) spill-free; h bf16-rn everywhere. Epilogue: 5 exp2 + 1.5 rcp /elem
// (4-gate paired rcp; c-tanh rcp paired across element pairs).
__global__ __launch_bounds__(512, 2) void lstm4f_k(
    const float* __restrict__ x,
    const u16* __restrict__ whh_hi, const u16* __restrict__ wih_hi2,
    const float* __restrict__ bih, const float* __restrict__ bhh,
    u16* __restrict__ hhi_g)
{
    __shared__ __align__(16) u16 Hhi[2][64][128];   // 32 KB (double-buffered)
    __shared__ __align__(16) u16 Hx[2][64][40];     // 10 KB (80B rows)
    const int tid = threadIdx.x;
    const int lane = tid & 63;
    const int wid = tid >> 6;
    const int j0 = wid * 16;
    const int l15 = lane & 15;
    const int lg = lane >> 4;          // 0..3
    const long seq0 = (long)blockIdx.x * 64;
    const int swzr = (l15 & 7) << 3;   // read-side XOR swizzle
    const int xs_seq = tid >> 3;       // x staging: 8 threads/seq-row
    const int xd0 = (tid & 7) * 2;

    // B fragments in registers: Whh (scaled bf16, 64 VGPR) + Wih (16 VGPR)
    short8v Bh[4][4];                  // [kt][gate]
    short8v b1[4];
    float bv[4];
#pragma unroll
    for (int kt = 0; kt < 4; ++kt)
#pragma unroll
        for (int g = 0; g < 4; ++g) {
            int row = g * NH + j0 + l15;
            Bh[kt][g] = *(const short8v*)(whh_hi + row * NH + kt * 32 + 8 * lg);
        }
#pragma unroll
    for (int g = 0; g < 4; ++g) {
        int row = g * NH + j0 + l15;
        b1[g] = *(const short8v*)(wih_hi2 + row * 32 + 8 * lg);
        bv[g] = (bih[row] + bhh[row]) * ((g == 2) ? N2L2E : NL2E);
    }

    // stage x for t=0 ([x_hi ; x_lo] halves)
    {
        float2 xv = *(const float2*)(x + ((seq0 + xs_seq) * NT + 0) * ND + xd0);
        unsigned int p0 = pack_split(xv.x), p1 = pack_split(xv.y);
        *(ushort2*)&Hx[0][xs_seq][xd0] = make_ushort2((u16)p0, (u16)p1);
        *(ushort2*)&Hx[0][xs_seq][16 + xd0] = make_ushort2((u16)(p0 >> 16), (u16)(p1 >> 16));
    }
    f32x4 c[4];
#pragma unroll
    for (int m = 0; m < 4; ++m) c[m] = (f32x4){0.f, 0.f, 0.f, 0.f};
    __syncthreads();

    for (int t = 0; t < NT; ++t) {
        const int cur = t & 1, nxt = cur ^ 1;
        float2 xv;
        if (t + 1 < NT)
            xv = *(const float2*)(x + ((seq0 + xs_seq) * NT + (t + 1)) * ND + xd0);

#pragma unroll
        for (int m = 0; m < 4; ++m) {
            const int sq = m * 16 + l15;
            short8v xa = *(const short8v*)&Hx[cur][sq][8 * lg];

            f32x4 acc[4];
#pragma unroll
            for (int g = 0; g < 4; ++g)
                acc[g] = (f32x4){bv[g], bv[g], bv[g], bv[g]};

            if (t > 0) {
#pragma unroll
                for (int kt = 0; kt < 4; ++kt) {
                    const int kk = (kt * 32 + 8 * lg) ^ swzr;
                    short8v ah = *(const short8v*)&Hhi[cur][sq][kk];
#pragma unroll
                    for (int g = 0; g < 4; ++g)
                        acc[g] = __builtin_amdgcn_mfma_f32_16x16x32_bf16(ah, Bh[kt][g], acc[g], 0, 0, 0);
                }
            }
#pragma unroll
            for (int g = 0; g < 4; ++g)
                acc[g] = __builtin_amdgcn_mfma_f32_16x16x32_bf16(xa, b1[g], acc[g], 0, 0, 0);

            // epilogue v2: 5 exp2 + 1.5 rcp per element
            float uc[4], so_[4];
#pragma unroll
            for (int r = 0; r < 4; ++r) {
                const float ui = exp2f(acc[0][r]);
                const float uf = exp2f(acc[1][r]);
                const float ug = exp2f(acc[2][r]);
                const float uo = exp2f(acc[3][r]);
                const float di = 1.f + ui, df = 1.f + uf;
                const float dg = 1.f + ug, dd = 1.f + uo;
                const float t1 = di * df, t2 = dg * dd;
                const float R = __builtin_amdgcn_rcpf(t1 * t2);
                const float Ra = R * t2;                    // 1/(di*df)
                const float Rb = R * t1;                    // 1/(dg*dd)
                const float si = Ra * df;                   // sigmoid(i)
                const float sf = Ra * di;                   // sigmoid(f)
                const float tg = fmaf(2.f, Rb * dd, -1.f);  // tanh(g)
                const float so = Rb * dg;                   // sigmoid(o)
                const float cc = fmaf(sf, c[m][r], si * tg);
                c[m][r] = cc;
                uc[r] = exp2f(cc * N2L2E);
                so_[r] = so;
            }
#pragma unroll
            for (int rp = 0; rp < 4; rp += 2) {             // paired c-tanh rcp
                const float q0 = 1.f + uc[rp], q1 = 1.f + uc[rp + 1];
                const float Rc = __builtin_amdgcn_rcpf(q0 * q1);
                const float rc0 = Rc * q1, rc1 = Rc * q0;
                const float hv0 = fmaf(2.f, so_[rp] * rc0, -so_[rp]);
                const float hv1 = fmaf(2.f, so_[rp + 1] * rc1, -so_[rp + 1]);
                const int sqa = m * 16 + 4 * lg + rp;
                const int sqb = sqa + 1;
                Hhi[nxt][sqa][(j0 + l15) ^ ((sqa & 7) << 3)] = bf16_rn(hv0);
                Hhi[nxt][sqb][(j0 + l15) ^ ((sqb & 7) << 3)] = bf16_rn(hv1);
            }
        }

        if (t + 1 < NT) {
            unsigned int p0 = pack_split(xv.x), p1 = pack_split(xv.y);
            *(ushort2*)&Hx[nxt][xs_seq][xd0] = make_ushort2((u16)p0, (u16)p1);
            *(ushort2*)&Hx[nxt][xs_seq][16 + xd0] = make_ushort2((u16)(p0 >> 16), (u16)(p1 >> 16));
        }
        __syncthreads();
    }

    // copy-out (node-major rows n*8+b): final h in Hhi[0]
    for (int ci = tid; ci < 1024; ci += 512) {
        int s = ci >> 4, g16 = ci & 15;
        int sg = g16 ^ (s & 7);
        unsigned int sglob = (unsigned int)(seq0 + s);
        unsigned int b = sglob / NN;
        unsigned int n = sglob - b * NN;
        uint4 v = *(const uint4*)&Hhi[0][s][sg * 8];
        *(uint4*)(hhi_g + ((long)n * 8 + b) * NH + g16 * 8) = v;
    }
}

// ---------- GCN GEMM: out = A @ W^T, single bf16 A plane, bf16 out ----------
__global__ __launch_bounds__(512) void gemmx4_k(
    const u16* __restrict__ Ah, const u16* __restrict__ Whi,
    u16* __restrict__ out)
{
    const int tid = threadIdx.x;
    const int lane = tid & 63;
    const int wid = tid >> 6;
    const int j0 = wid * 16;
    const int l15 = lane & 15;
    const int lg = lane >> 4;
    const long row0 = (long)blockIdx.x * 64;

    short8v Bh[4];
#pragma unroll
    for (int kt = 0; kt < 4; ++kt)
        Bh[kt] = *(const short8v*)(Whi + (j0 + l15) * NH + kt * 32 + 8 * lg);

#pragma unroll
    for (int m = 0; m < 4; ++m) {
        f32x4 acc = (f32x4){0.f, 0.f, 0.f, 0.f};
#pragma unroll
        for (int kt = 0; kt < 4; ++kt) {
            long ar = (row0 + m * 16 + l15) * NH + kt * 32 + 8 * lg;
            short8v ah = *(const short8v*)(Ah + ar);
            acc = __builtin_amdgcn_mfma_f32_16x16x32_bf16(ah, Bh[kt], acc, 0, 0, 0);
        }
#pragma unroll
        for (int r = 0; r < 4; ++r)
            out[(row0 + m * 16 + 4 * lg + r) * NH + j0 + l15] = bf16_rn(acc[r]);
    }
}

// ---------------- degree accumulation ---------------------------------------
__global__ void degacc_k(const int* __restrict__ ei, const float* __restrict__ ew,
                         float* deg, int* cnt) {
    int e = blockIdx.x * 256 + threadIdx.x;
    if (e < NE) {
        int d = ei[NE + e];
        atomicAdd(&deg[d], ew[e]);
        atomicAdd(&cnt[d], 1);
    }
}

// ---------------- scan (+ dinv) ---------------------------------------------
__global__ __launch_bounds__(1024) void scan_k(const int* __restrict__ cnt,
                                               int* __restrict__ rowp,
                                               const float* __restrict__ deg,
                                               float* __restrict__ dinv) {
    for (int idx = threadIdx.x; idx < NN; idx += 1024) {
        float d = deg[idx];
        dinv[idx] = d > 0.f ? rsqrtf(d) : 0.f;
    }
    __shared__ int sA[1024];
    __shared__ int sB[1024];
    const int tid = threadIdx.x;
    const int CH = 10;
    int base = tid * CH;
    int local[CH];
    int ssum = 0;
#pragma unroll
    for (int i = 0; i < CH; ++i) {
        int idx = base + i;
        int v = (idx < NN) ? cnt[idx] : 0;
        local[i] = v; ssum += v;
    }
    int* src = sA; int* dst = sB;
    src[tid] = ssum;
    __syncthreads();
    for (int off = 1; off < 1024; off <<= 1) {
        int v = src[tid];
        if (tid >= off) v += src[tid - off];
        dst[tid] = v;
        __syncthreads();
        int* tmp = src; src = dst; dst = tmp;
    }
    int run = src[tid] - ssum;
#pragma unroll
    for (int i = 0; i < CH; ++i) {
        int idx = base + i;
        if (idx < NN) rowp[idx] = run;
        run += local[i];
    }
    if (tid == 1023) rowp[NN] = src[1023];
}

__global__ void scatter_k(const int* __restrict__ ei, const float* __restrict__ ew,
                          const float* __restrict__ dinv, const int* __restrict__ rowp,
                          int* fill, int* __restrict__ col, float* __restrict__ val)
{
    int e = blockIdx.x * 256 + threadIdx.x;
    if (e >= NE) return;
    int srcn = ei[e], d = ei[NE + e];
    int pos = rowp[d] + atomicAdd(&fill[d], 1);
    col[pos] = srcn;
    val[pos] = dinv[srcn] * ew[e] * dinv[d];
}

// ---------- gather A (GCN layer 1): no LDS, dual accumulators, bf16 out -----
__global__ __launch_bounds__(256) void gatherA_k(const u16* __restrict__ xlb,
    const int* __restrict__ rowp, const int* __restrict__ col,
    const float* __restrict__ val, const float* __restrict__ dinv,
    const float* __restrict__ bias, u16* __restrict__ ohi)
{
    const int n = blockIdx.x;
    const int tid = threadIdx.x;
    const int q = tid & 31;
    const float dn = dinv[n];
    const float sn = dn * dn;
    float4 accA, accB = make_float4(0.f, 0.f, 0.f, 0.f);
    {
        ushort4 u = *(const ushort4*)(xlb + (long)n * 1024 + tid * 4);
        accA.x = sn * bf16f(u.x); accA.y = sn * bf16f(u.y);
        accA.z = sn * bf16f(u.z); accA.w = sn * bf16f(u.w);
    }
    int e = rowp[n];
    const int e1 = rowp[n + 1];
    for (; e + 2 <= e1; e += 2) {
        const int s0 = col[e], s1 = col[e + 1];
        const float w0 = val[e], w1 = val[e + 1];
        const ushort4 u0 = *(const ushort4*)(xlb + (long)s0 * 1024 + tid * 4);
        const ushort4 u1 = *(const ushort4*)(xlb + (long)s1 * 1024 + tid * 4);
        accA.x = fmaf(w0, bf16f(u0.x), accA.x); accA.y = fmaf(w0, bf16f(u0.y), accA.y);
        accA.z = fmaf(w0, bf16f(u0.z), accA.z); accA.w = fmaf(w0, bf16f(u0.w), accA.w);
        accB.x = fmaf(w1, bf16f(u1.x), accB.x); accB.y = fmaf(w1, bf16f(u1.y), accB.y);
        accB.z = fmaf(w1, bf16f(u1.z), accB.z); accB.w = fmaf(w1, bf16f(u1.w), accB.w);
    }
    if (e < e1) {
        const int s0 = col[e];
        const float w0 = val[e];
        const ushort4 u0 = *(const ushort4*)(xlb + (long)s0 * 1024 + tid * 4);
        accA.x = fmaf(w0, bf16f(u0.x), accA.x); accA.y = fmaf(w0, bf16f(u0.y), accA.y);
        accA.z = fmaf(w0, bf16f(u0.z), accA.z); accA.w = fmaf(w0, bf16f(u0.w), accA.w);
    }
    const float4 bb = ((const float4*)bias)[q];
    ushort4 h4 = make_ushort4(
        bf16_rn(fmaxf(accA.x + accB.x + bb.x, 0.f)),
        bf16_rn(fmaxf(accA.y + accB.y + bb.y, 0.f)),
        bf16_rn(fmaxf(accA.z + accB.z + bb.z, 0.f)),
        bf16_rn(fmaxf(accA.w + accB.w + bb.w, 0.f)));
    *(ushort4*)(ohi + (long)n * 1024 + tid * 4) = h4;
}

// ---------- gather B (GCN layer 2 + fused FC) -------------------------------
__global__ __launch_bounds__(256) void gatherB_k(const u16* __restrict__ xlb,
    const int* __restrict__ rowp, const int* __restrict__ col,
    const float* __restrict__ val, const float* __restrict__ dinv,
    const float* __restrict__ bias,
    const float* __restrict__ fcw, const float* __restrict__ fcb,
    float* __restrict__ out)
{
    __shared__ float hrow[8][132];
    __shared__ float wl[16][132];
    const int n = blockIdx.x;
    const int tid = threadIdx.x;
    const int q = tid & 31;
    for (int l = tid; l < 16 * 128; l += 256)
        wl[l >> 7][l & 127] = fcw[l];
    const float dn = dinv[n];
    const float sn = dn * dn;
    float4 accA, accB = make_float4(0.f, 0.f, 0.f, 0.f);
    {
        ushort4 u = *(const ushort4*)(xlb + (long)n * 1024 + tid * 4);
        accA.x = sn * bf16f(u.x); accA.y = sn * bf16f(u.y);
        accA.z = sn * bf16f(u.z); accA.w = sn * bf16f(u.w);
    }
    int e = rowp[n];
    const int e1 = rowp[n + 1];
    for (; e + 2 <= e1; e += 2) {
        const int s0 = col[e], s1 = col[e + 1];
        const float w0 = val[e], w1 = val[e + 1];
        const ushort4 u0 = *(const ushort4*)(xlb + (long)s0 * 1024 + tid * 4);
        const ushort4 u1 = *(const ushort4*)(xlb + (long)s1 * 1024 + tid * 4);
        accA.x = fmaf(w0, bf16f(u0.x), accA.x); accA.y = fmaf(w0, bf16f(u0.y), accA.y);
        accA.z = fmaf(w0, bf16f(u0.z), accA.z); accA.w = fmaf(w0, bf16f(u0.w), accA.w);
        accB.x = fmaf(w1, bf16f(u1.x), accB.x); accB.y = fmaf(w1, bf16f(u1.y), accB.y);
        accB.z = fmaf(w1, bf16f(u1.z), accB.z); accB.w = fmaf(w1, bf16f(u1.w), accB.w);
    }
    if (e < e1) {
        const int s0 = col[e];
        const float w0 = val[e];
        const ushort4 u0 = *(const ushort4*)(xlb + (long)s0 * 1024 + tid * 4);
        accA.x = fmaf(w0, bf16f(u0.x), accA.x); accA.y = fmaf(w0, bf16f(u0.y), accA.y);
        accA.z = fmaf(w0, bf16f(u0.z), accA.z); accA.w = fmaf(w0, bf16f(u0.w), accA.w);
    }
    const float4 bb = ((const float4*)bias)[q];
    const int b = tid >> 5;
    *(float4*)&hrow[b][q * 4] = make_float4(
        fmaxf(accA.x + accB.x + bb.x, 0.f),
        fmaxf(accA.y + accB.y + bb.y, 0.f),
        fmaxf(accA.z + accB.z + bb.z, 0.f),
        fmaxf(accA.w + accB.w + bb.w, 0.f));
    __syncthreads();
    if (tid < 128) {
        const int b2 = tid >> 4, o = tid & 15;
        float a = fcb[o];
#pragma unroll 8
        for (int k = 0; k < NH; ++k) a = fmaf(hrow[b2][k], wl[o][k], a);
        out[((long)b2 * NN + n) * 16 + o] = a;
    }
}

// ---------------------------------------------------------------------------
extern "C" void kernel_launch(void* const* d_in, const int* in_sizes, int n_in,
                              void* d_out, int out_size, void* d_ws, size_t ws_size,
                              hipStream_t stream)
{
    const float* x   = (const float*)d_in[0];
    const int*   ei  = (const int*)d_in[1];
    const float* ew  = (const float*)d_in[2];
    const float* Wih = (const float*)d_in[3];
    const float* Whh = (const float*)d_in[4];
    const float* bih = (const float*)d_in[5];
    const float* bhh = (const float*)d_in[6];
    const float* g1w = (const float*)d_in[7];
    const float* g1b = (const float*)d_in[8];
    const float* g2w = (const float*)d_in[9];
    const float* g2b = (const float*)d_in[10];
    const float* fcw = (const float*)d_in[11];
    const float* fcb = (const float*)d_in[12];
    float* out = (float*)d_out;

    char* ws = (char*)d_ws;
    u16* whh_hi  = (u16*)(ws + 0);           // 131072
    u16* wih_hi2 = (u16*)(ws + 131072);      // 32768
    u16* g1hi    = (u16*)(ws + 196608);      // 32768
    u16* g2hi    = (u16*)(ws + 229376);      // 32768
    float* deg   = (float*)(ws + 262144);
    float* dinv  = (float*)(ws + 303104);
    int*   cnt   = (int*)(ws + 344064);
    int*   fill  = (int*)(ws + 385024);
    int*   rowp  = (int*)(ws + 425984);
    int*   col   = (int*)(ws + 466176);      // 640000
    float* val   = (float*)(ws + 1106176);   // 640000
    u16* hhi     = (u16*)(ws + 2097152);     // 20480000 (node-major bf16)
    u16* xlb     = (u16*)(ws + 22577152);    // 20480000 (node-major bf16)

    prep_w_k<<<256, 256, 0, stream>>>(Whh, Wih, g1w, g2w, whh_hi, wih_hi2,
                                      g1hi, g2hi, deg, cnt, fill);
    lstm4f_k<<<BN / 64, 512, 0, stream>>>(x, whh_hi, wih_hi2, bih, bhh, hhi);

    degacc_k<<<(NE + 255) / 256, 256, 0, stream>>>(ei, ew, deg, cnt);
    scan_k<<<1, 1024, 0, stream>>>(cnt, rowp, deg, dinv);
    scatter_k<<<(NE + 255) / 256, 256, 0, stream>>>(ei, ew, dinv, rowp, fill, col, val);

    gemmx4_k<<<BN / 64, 512, 0, stream>>>(hhi, g1hi, xlb);
    gatherA_k<<<NN, 256, 0, stream>>>(xlb, rowp, col, val, dinv, g1b, hhi);
    gemmx4_k<<<BN / 64, 512, 0, stream>>>(hhi, g2hi, xlb);
    gatherB_k<<<NN, 256, 0, stream>>>(xlb, rowp, col, val, dinv, g2b,
                                      fcw, fcb, out);
}

// Round 15
// 471.773 us; speedup vs baseline: 2.3846x; 1.0209x over previous
//
#include <hip/hip_runtime.h>
#include <math.h>

#define NB 8
#define NN 10000
#define NT 12
#define ND 16
#define NH 128
#define NE 160000
#define BN (NB * NN)  // 80000

typedef __attribute__((ext_vector_type(8))) short short8v;
typedef __attribute__((ext_vector_type(4))) float f32x4;
typedef unsigned short u16;

#define NL2E  -1.442695041f   // -log2(e)
#define N2L2E -2.885390082f   // -2*log2(e)

__device__ __forceinline__ u16 bf16_rn(float f) {
    unsigned int u = __float_as_uint(f);
    u += 0x7fffu + ((u >> 16) & 1u);
    return (u16)(u >> 16);
}
__device__ __forceinline__ float bf16f(u16 s) {
    return __uint_as_float((unsigned int)s << 16);
}
// trunc-hi + rn-lo split packed as (lo<<16)|hi  (x staging keeps hi/lo)
__device__ __forceinline__ unsigned int pack_split(float f) {
    unsigned int u = __float_as_uint(f);
    unsigned int hh = u >> 16;
    float rem = f - __uint_as_float(u & 0xffff0000u);
    unsigned int hl = bf16_rn(rem);
    return (hl << 16) | hh;
}

// ---------- prep: scaled bf16 weights (exp2 gates) + CSR init ---------------
__global__ void prep_w_k(const float* __restrict__ Whh, const float* __restrict__ Wih,
                         const float* __restrict__ g1w, const float* __restrict__ g2w,
                         u16* __restrict__ whh_hi, u16* __restrict__ wih_hi2,
                         u16* __restrict__ g1hi, u16* __restrict__ g2hi,
                         float* __restrict__ deg, int* __restrict__ cnt, int* __restrict__ fill)
{
    int i = blockIdx.x * 256 + threadIdx.x;   // 65536 threads
    if (i < 512 * 128) {
        int j = i >> 7;
        float s = ((j >> 7) == 2) ? N2L2E : NL2E;
        whh_hi[i] = bf16_rn(s * Whh[i]);
    }
    if (i < 512 * 16) {
        int row = i >> 4, d = i & 15;
        float s = ((row >> 7) == 2) ? N2L2E : NL2E;
        u16 h = bf16_rn(s * Wih[i]);
        wih_hi2[row * 32 + d] = h;        // duplicated: pairs with [x_hi; x_lo]
        wih_hi2[row * 32 + 16 + d] = h;
    }
    if (i < 128 * 128) {
        g1hi[i] = bf16_rn(g1w[i]);
        g2hi[i] = bf16_rn(g2w[i]);
    }
    if (i < NN) { deg[i] = 1.0f; cnt[i] = 0; fill[i] = 0; }   // 1.0 = self-loop
}

// ---------- LSTM v4d (round-12 proven, 321 us): single-plane, exp2 ----------
__global__ __launch_bounds__(512, 2) void lstm4d_k(
    const float* __restrict__ x,
    const u16* __restrict__ whh_hi, const u16* __restrict__ wih_hi2,
    const float* __restrict__ bih, const float* __restrict__ bhh,
    u16* __restrict__ hhi_g)
{
    __shared__ __align__(16) u16 Hhi[2][64][128];   // 32 KB (double-buffered)
    __shared__ __align__(16) u16 Hx[2][64][40];     // 10 KB (80B rows)
    const int tid = threadIdx.x;
    const int lane = tid & 63;
    const int wid = tid >> 6;
    const int j0 = wid * 16;
    const int l15 = lane & 15;
    const int lg = lane >> 4;          // 0..3
    const long seq0 = (long)blockIdx.x * 64;
    const int swzr = (l15 & 7) << 3;   // read-side XOR swizzle
    const int xs_seq = tid >> 3;       // x staging: 8 threads/seq-row
    const int xd0 = (tid & 7) * 2;

    short8v Bh[4][4];                  // [kt][gate]
    short8v b1[4];
    float bv[4];
#pragma unroll
    for (int kt = 0; kt < 4; ++kt)
#pragma unroll
        for (int g = 0; g < 4; ++g) {
            int row = g * NH + j0 + l15;
            Bh[kt][g] = *(const short8v*)(whh_hi + row * NH + kt * 32 + 8 * lg);
        }
#pragma unroll
    for (int g = 0; g < 4; ++g) {
        int row = g * NH + j0 + l15;
        b1[g] = *(const short8v*)(wih_hi2 + row * 32 + 8 * lg);
        bv[g] = (bih[row] + bhh[row]) * ((g == 2) ? N2L2E : NL2E);
    }

    {
        float2 xv = *(const float2*)(x + ((seq0 + xs_seq) * NT + 0) * ND + xd0);
        unsigned int p0 = pack_split(xv.x), p1 = pack_split(xv.y);
        *(ushort2*)&Hx[0][xs_seq][xd0] = make_ushort2((u16)p0, (u16)p1);
        *(ushort2*)&Hx[0][xs_seq][16 + xd0] = make_ushort2((u16)(p0 >> 16), (u16)(p1 >> 16));
    }
    f32x4 c[4];
#pragma unroll
    for (int m = 0; m < 4; ++m) c[m] = (f32x4){0.f, 0.f, 0.f, 0.f};
    __syncthreads();

    for (int t = 0; t < NT; ++t) {
        const int cur = t & 1, nxt = cur ^ 1;
        float2 xv;
        if (t + 1 < NT)
            xv = *(const float2*)(x + ((seq0 + xs_seq) * NT + (t + 1)) * ND + xd0);

#pragma unroll
        for (int m = 0; m < 4; ++m) {
            const int sq = m * 16 + l15;
            short8v xa = *(const short8v*)&Hx[cur][sq][8 * lg];

            f32x4 acc[4];
#pragma unroll
            for (int g = 0; g < 4; ++g)
                acc[g] = (f32x4){bv[g], bv[g], bv[g], bv[g]};

            if (t > 0) {
#pragma unroll
                for (int kt = 0; kt < 4; ++kt) {
                    const int kk = (kt * 32 + 8 * lg) ^ swzr;
                    short8v ah = *(const short8v*)&Hhi[cur][sq][kk];
#pragma unroll
                    for (int g = 0; g < 4; ++g)
                        acc[g] = __builtin_amdgcn_mfma_f32_16x16x32_bf16(ah, Bh[kt][g], acc[g], 0, 0, 0);
                }
            }
#pragma unroll
            for (int g = 0; g < 4; ++g)
                acc[g] = __builtin_amdgcn_mfma_f32_16x16x32_bf16(xa, b1[g], acc[g], 0, 0, 0);

#pragma unroll
            for (int r = 0; r < 4; ++r) {
                const float ui = exp2f(acc[0][r]);
                const float uf = exp2f(acc[1][r]);
                const float ug = exp2f(acc[2][r]);
                const float uo = exp2f(acc[3][r]);
                const float di = 1.f + ui, df = 1.f + uf;
                const float dg = 1.f + ug, dd = 1.f + uo;
                const float r0 = __builtin_amdgcn_rcpf(di * df);
                const float r1 = __builtin_amdgcn_rcpf(dg * dd);
                const float si = r0 * df;
                const float sf = r0 * di;
                const float tg = fmaf(2.f, r1 * dd, -1.f);
                const float so = r1 * dg;
                const float cc = fmaf(sf, c[m][r], si * tg);
                c[m][r] = cc;
                const float uc = exp2f(cc * N2L2E);
                const float rc = __builtin_amdgcn_rcpf(1.f + uc);
                const float hv = fmaf(2.f, so * rc, -so);
                const int sq2 = m * 16 + 4 * lg + r;
                const int jj = (j0 + l15) ^ ((sq2 & 7) << 3);
                Hhi[nxt][sq2][jj] = bf16_rn(hv);
            }
        }

        if (t + 1 < NT) {
            unsigned int p0 = pack_split(xv.x), p1 = pack_split(xv.y);
            *(ushort2*)&Hx[nxt][xs_seq][xd0] = make_ushort2((u16)p0, (u16)p1);
            *(ushort2*)&Hx[nxt][xs_seq][16 + xd0] = make_ushort2((u16)(p0 >> 16), (u16)(p1 >> 16));
        }
        __syncthreads();
    }

    // copy-out (node-major rows n*8+b): final h in Hhi[0]
    for (int ci = tid; ci < 1024; ci += 512) {
        int s = ci >> 4, g16 = ci & 15;
        int sg = g16 ^ (s & 7);
        unsigned int sglob = (unsigned int)(seq0 + s);
        unsigned int b = sglob / NN;
        unsigned int n = sglob - b * NN;
        uint4 v = *(const uint4*)&Hhi[0][s][sg * 8];
        *(uint4*)(hhi_g + ((long)n * 8 + b) * NH + g16 * 8) = v;
    }
}

// ---------------- degree accumulation ---------------------------------------
__global__ void degacc_k(const int* __restrict__ ei, const float* __restrict__ ew,
                         float* deg, int* cnt) {
    int e = blockIdx.x * 256 + threadIdx.x;
    if (e < NE) {
        int d = ei[NE + e];
        atomicAdd(&deg[d], ew[e]);
        atomicAdd(&cnt[d], 1);
    }
}

// ---------------- scan (+ dinv) ---------------------------------------------
__global__ __launch_bounds__(1024) void scan_k(const int* __restrict__ cnt,
                                               int* __restrict__ rowp,
                                               const float* __restrict__ deg,
                                               float* __restrict__ dinv) {
    for (int idx = threadIdx.x; idx < NN; idx += 1024) {
        float d = deg[idx];
        dinv[idx] = d > 0.f ? rsqrtf(d) : 0.f;
    }
    __shared__ int sA[1024];
    __shared__ int sB[1024];
    const int tid = threadIdx.x;
    const int CH = 10;
    int base = tid * CH;
    int local[CH];
    int ssum = 0;
#pragma unroll
    for (int i = 0; i < CH; ++i) {
        int idx = base + i;
        int v = (idx < NN) ? cnt[idx] : 0;
        local[i] = v; ssum += v;
    }
    int* src = sA; int* dst = sB;
    src[tid] = ssum;
    __syncthreads();
    for (int off = 1; off < 1024; off <<= 1) {
        int v = src[tid];
        if (tid >= off) v += src[tid - off];
        dst[tid] = v;
        __syncthreads();
        int* tmp = src; src = dst; dst = tmp;
    }
    int run = src[tid] - ssum;
#pragma unroll
    for (int i = 0; i < CH; ++i) {
        int idx = base + i;
        if (idx < NN) rowp[idx] = run;
        run += local[i];
    }
    if (tid == 1023) rowp[NN] = src[1023];
}

__global__ void scatter_k(const int* __restrict__ ei, const float* __restrict__ ew,
                          const float* __restrict__ dinv, const int* __restrict__ rowp,
                          int* fill, int* __restrict__ col, float* __restrict__ val)
{
    int e = blockIdx.x * 256 + threadIdx.x;
    if (e >= NE) return;
    int srcn = ei[e], d = ei[NE + e];
    int pos = rowp[d] + atomicAdd(&fill[d], 1);
    col[pos] = srcn;
    val[pos] = dinv[srcn] * ew[e] * dinv[d];
}

// ---------- fused GCN layer: agg(h) then @W^T + b + relu (commuted order) ---
// One block per node, 256 threads. LAST=1 additionally applies the final FC.
// A-tile: agg rows 0-7 (batches), rows 8-15 zero-pad; XOR-swizzled LDS.
template<int LAST>
__global__ __launch_bounds__(256) void gcn_fused_k(const u16* __restrict__ hin,
    const int* __restrict__ rowp, const int* __restrict__ col,
    const float* __restrict__ val, const float* __restrict__ dinv,
    const float* __restrict__ bias, const u16* __restrict__ Whi,
    u16* __restrict__ hout,
    const float* __restrict__ fcw, const float* __restrict__ fcb,
    float* __restrict__ out)
{
    __shared__ __align__(16) u16 Ag[16][128];    // swizzled agg (rows 8-15 = 0)
    __shared__ __align__(16) u16 Ou[8][128];     // bf16 output staging (!LAST)
    __shared__ float hrow[8][132];               // f32 output staging (LAST)
    __shared__ float wl[16][132];                // fc weights (LAST)
    const int n = blockIdx.x;
    const int tid = threadIdx.x;
    const int b = tid >> 5;            // batch 0..7
    const int q = tid & 31;            // 4-channel slot

    // zero pad rows 8..15 (128 uint4 = 2048 B)
    if (tid < 128) *(uint4*)&Ag[8 + (tid >> 4)][(tid & 15) * 8] = make_uint4(0, 0, 0, 0);
    if (LAST) {
        for (int l = tid; l < 16 * 128; l += 256)
            wl[l >> 7][l & 127] = fcw[l];
    }

    // ---- aggregation (node-major bf16 rows, dual accumulators) ----
    const float dn = dinv[n];
    const float sn = dn * dn;
    float4 accA, accB = make_float4(0.f, 0.f, 0.f, 0.f);
    {
        ushort4 u = *(const ushort4*)(hin + (long)n * 1024 + tid * 4);
        accA.x = sn * bf16f(u.x); accA.y = sn * bf16f(u.y);
        accA.z = sn * bf16f(u.z); accA.w = sn * bf16f(u.w);
    }
    int e = rowp[n];
    const int e1 = rowp[n + 1];
    for (; e + 2 <= e1; e += 2) {
        const int s0 = col[e], s1 = col[e + 1];
        const float w0 = val[e], w1 = val[e + 1];
        const ushort4 u0 = *(const ushort4*)(hin + (long)s0 * 1024 + tid * 4);
        const ushort4 u1 = *(const ushort4*)(hin + (long)s1 * 1024 + tid * 4);
        accA.x = fmaf(w0, bf16f(u0.x), accA.x); accA.y = fmaf(w0, bf16f(u0.y), accA.y);
        accA.z = fmaf(w0, bf16f(u0.z), accA.z); accA.w = fmaf(w0, bf16f(u0.w), accA.w);
        accB.x = fmaf(w1, bf16f(u1.x), accB.x); accB.y = fmaf(w1, bf16f(u1.y), accB.y);
        accB.z = fmaf(w1, bf16f(u1.z), accB.z); accB.w = fmaf(w1, bf16f(u1.w), accB.w);
    }
    if (e < e1) {
        const int s0 = col[e];
        const float w0 = val[e];
        const ushort4 u0 = *(const ushort4*)(hin + (long)s0 * 1024 + tid * 4);
        accA.x = fmaf(w0, bf16f(u0.x), accA.x); accA.y = fmaf(w0, bf16f(u0.y), accA.y);
        accA.z = fmaf(w0, bf16f(u0.z), accA.z); accA.w = fmaf(w0, bf16f(u0.w), accA.w);
    }
    // write agg row (bf16, swizzled): elements (q*4..q*4+3) ^ ((b&7)<<3)
    {
        ushort4 a4 = make_ushort4(bf16_rn(accA.x + accB.x), bf16_rn(accA.y + accB.y),
                                  bf16_rn(accA.z + accB.z), bf16_rn(accA.w + accB.w));
        *(ushort4*)&Ag[b][(q * 4) ^ ((b & 7) << 3)] = a4;
    }
    __syncthreads();

    // ---- per-node transform: (16x128 padded A) @ W^T via MFMA ----
    const int lane = tid & 63;
    const int wid = tid >> 6;          // 0..3, each wave: 2 N-tiles
    const int l15 = lane & 15;
    const int lg = lane >> 4;
    const int swzA = (l15 & 7) << 3;
#pragma unroll
    for (int jt = 0; jt < 2; ++jt) {
        const int j0 = (wid * 2 + jt) * 16;
        f32x4 acc = (f32x4){0.f, 0.f, 0.f, 0.f};
#pragma unroll
        for (int kt = 0; kt < 4; ++kt) {
            short8v ah = *(const short8v*)&Ag[l15][(kt * 32 + 8 * lg) ^ swzA];
            short8v bh = *(const short8v*)(Whi + (j0 + l15) * NH + kt * 32 + 8 * lg);
            acc = __builtin_amdgcn_mfma_f32_16x16x32_bf16(ah, bh, acc, 0, 0, 0);
        }
        if (lg < 2) {                  // valid rows 0..7
            const float bj = bias[j0 + l15];
#pragma unroll
            for (int r = 0; r < 4; ++r) {
                const int row = 4 * lg + r;
                const float v = fmaxf(acc[r] + bj, 0.f);
                if (LAST) hrow[row][j0 + l15] = v;
                else      Ou[row][j0 + l15] = bf16_rn(v);
            }
        }
    }
    __syncthreads();

    if (LAST) {
        if (tid < 128) {
            const int b2 = tid >> 4, o = tid & 15;
            float a = fcb[o];
#pragma unroll 8
            for (int k = 0; k < NH; ++k) a = fmaf(hrow[b2][k], wl[o][k], a);
            out[((long)b2 * NN + n) * 16 + o] = a;
        }
    } else {
        if (tid < 128)                 // 2 KB contiguous copy-out
            *(uint4*)(hout + (long)n * 1024 + tid * 8) = *(const uint4*)&Ou[tid >> 4][(tid & 15) * 8];
    }
}

// ---------------------------------------------------------------------------
extern "C" void kernel_launch(void* const* d_in, const int* in_sizes, int n_in,
                              void* d_out, int out_size, void* d_ws, size_t ws_size,
                              hipStream_t stream)
{
    const float* x   = (const float*)d_in[0];
    const int*   ei  = (const int*)d_in[1];
    const float* ew  = (const float*)d_in[2];
    const float* Wih = (const float*)d_in[3];
    const float* Whh = (const float*)d_in[4];
    const float* bih = (const float*)d_in[5];
    const float* bhh = (const float*)d_in[6];
    const float* g1w = (const float*)d_in[7];
    const float* g1b = (const float*)d_in[8];
    const float* g2w = (const float*)d_in[9];
    const float* g2b = (const float*)d_in[10];
    const float* fcw = (const float*)d_in[11];
    const float* fcb = (const float*)d_in[12];
    float* out = (float*)d_out;

    char* ws = (char*)d_ws;
    u16* whh_hi  = (u16*)(ws + 0);           // 131072
    u16* wih_hi2 = (u16*)(ws + 131072);      // 32768
    u16* g1hi    = (u16*)(ws + 196608);      // 32768
    u16* g2hi    = (u16*)(ws + 229376);      // 32768
    float* deg   = (float*)(ws + 262144);
    float* dinv  = (float*)(ws + 303104);
    int*   cnt   = (int*)(ws + 344064);
    int*   fill  = (int*)(ws + 385024);
    int*   rowp  = (int*)(ws + 425984);
    int*   col   = (int*)(ws + 466176);      // 640000
    float* val   = (float*)(ws + 1106176);   // 640000
    u16* hhi     = (u16*)(ws + 2097152);     // 20480000 (node-major bf16)
    u16* h1      = (u16*)(ws + 22577152);    // 20480000 (node-major bf16)

    prep_w_k<<<256, 256, 0, stream>>>(Whh, Wih, g1w, g2w, whh_hi, wih_hi2,
                                      g1hi, g2hi, deg, cnt, fill);
    lstm4d_k<<<BN / 64, 512, 0, stream>>>(x, whh_hi, wih_hi2, bih, bhh, hhi);

    degacc_k<<<(NE + 255) / 256, 256, 0, stream>>>(ei, ew, deg, cnt);
    scan_k<<<1, 1024, 0, stream>>>(cnt, rowp, deg, dinv);
    scatter_k<<<(NE + 255) / 256, 256, 0, stream>>>(ei, ew, dinv, rowp, fill, col, val);

    gcn_fused_k<0><<<NN, 256, 0, stream>>>(hhi, rowp, col, val, dinv, g1b, g1hi,
                                           h1, nullptr, nullptr, nullptr);
    gcn_fused_k<1><<<NN, 256, 0, stream>>>(h1, rowp, col, val, dinv, g2b, g2hi,
                                           nullptr, fcw, fcb, out);
}

// Round 16
// 414.332 us; speedup vs baseline: 2.7152x; 1.1386x over previous
//
#include <hip/hip_runtime.h>
#include <math.h>

#define NB 8
#define NN 10000
#define NT 12
#define ND 16
#define NH 128
#define NE 160000
#define BN (NB * NN)  // 80000

typedef __attribute__((ext_vector_type(8))) short short8v;
typedef __attribute__((ext_vector_type(4))) float f32x4;
typedef unsigned short u16;

#define NL2E  -1.442695041f   // -log2(e)
#define N2L2E -2.885390082f   // -2*log2(e)

__device__ __forceinline__ u16 bf16_rn(float f) {
    unsigned int u = __float_as_uint(f);
    u += 0x7fffu + ((u >> 16) & 1u);
    return (u16)(u >> 16);
}
__device__ __forceinline__ float bf16f(u16 s) {
    return __uint_as_float((unsigned int)s << 16);
}
// trunc-hi + rn-lo split packed as (lo<<16)|hi  (x staging keeps hi/lo)
__device__ __forceinline__ unsigned int pack_split(float f) {
    unsigned int u = __float_as_uint(f);
    unsigned int hh = u >> 16;
    float rem = f - __uint_as_float(u & 0xffff0000u);
    unsigned int hl = bf16_rn(rem);
    return (hl << 16) | hh;
}

// ---------- prep: scaled bf16 weights (exp2 gates) + CSR init ---------------
__global__ void prep_w_k(const float* __restrict__ Whh, const float* __restrict__ Wih,
                         const float* __restrict__ g1w, const float* __restrict__ g2w,
                         u16* __restrict__ whh_hi, u16* __restrict__ wih_hi2,
                         u16* __restrict__ g1hi, u16* __restrict__ g2hi,
                         float* __restrict__ deg, int* __restrict__ cnt, int* __restrict__ fill)
{
    int i = blockIdx.x * 256 + threadIdx.x;   // 65536 threads
    if (i < 512 * 128) {
        int j = i >> 7;
        float s = ((j >> 7) == 2) ? N2L2E : NL2E;
        whh_hi[i] = bf16_rn(s * Whh[i]);
    }
    if (i < 512 * 16) {
        int row = i >> 4, d = i & 15;
        float s = ((row >> 7) == 2) ? N2L2E : NL2E;
        u16 h = bf16_rn(s * Wih[i]);
        wih_hi2[row * 32 + d] = h;        // duplicated: pairs with [x_hi; x_lo]
        wih_hi2[row * 32 + 16 + d] = h;
    }
    if (i < 128 * 128) {
        g1hi[i] = bf16_rn(g1w[i]);
        g2hi[i] = bf16_rn(g2w[i]);
    }
    if (i < NN) { deg[i] = 1.0f; cnt[i] = 0; fill[i] = 0; }   // 1.0 = self-loop
}

// ---------- LSTM v4d (round-12 proven): single-plane, exp2 builtin ----------
__global__ __launch_bounds__(512, 2) void lstm4d_k(
    const float* __restrict__ x,
    const u16* __restrict__ whh_hi, const u16* __restrict__ wih_hi2,
    const float* __restrict__ bih, const float* __restrict__ bhh,
    u16* __restrict__ hhi_g)
{
    __shared__ __align__(16) u16 Hhi[2][64][128];   // 32 KB (double-buffered)
    __shared__ __align__(16) u16 Hx[2][64][40];     // 10 KB (80B rows)
    const int tid = threadIdx.x;
    const int lane = tid & 63;
    const int wid = tid >> 6;
    const int j0 = wid * 16;
    const int l15 = lane & 15;
    const int lg = lane >> 4;          // 0..3
    const long seq0 = (long)blockIdx.x * 64;
    const int swzr = (l15 & 7) << 3;   // read-side XOR swizzle
    const int xs_seq = tid >> 3;       // x staging: 8 threads/seq-row
    const int xd0 = (tid & 7) * 2;

    short8v Bh[4][4];                  // [kt][gate]
    short8v b1[4];
    float bv[4];
#pragma unroll
    for (int kt = 0; kt < 4; ++kt)
#pragma unroll
        for (int g = 0; g < 4; ++g) {
            int row = g * NH + j0 + l15;
            Bh[kt][g] = *(const short8v*)(whh_hi + row * NH + kt * 32 + 8 * lg);
        }
#pragma unroll
    for (int g = 0; g < 4; ++g) {
        int row = g * NH + j0 + l15;
        b1[g] = *(const short8v*)(wih_hi2 + row * 32 + 8 * lg);
        bv[g] = (bih[row] + bhh[row]) * ((g == 2) ? N2L2E : NL2E);
    }

    {
        float2 xv = *(const float2*)(x + ((seq0 + xs_seq) * NT + 0) * ND + xd0);
        unsigned int p0 = pack_split(xv.x), p1 = pack_split(xv.y);
        *(ushort2*)&Hx[0][xs_seq][xd0] = make_ushort2((u16)p0, (u16)p1);
        *(ushort2*)&Hx[0][xs_seq][16 + xd0] = make_ushort2((u16)(p0 >> 16), (u16)(p1 >> 16));
    }
    f32x4 c[4];
#pragma unroll
    for (int m = 0; m < 4; ++m) c[m] = (f32x4){0.f, 0.f, 0.f, 0.f};
    __syncthreads();

    for (int t = 0; t < NT; ++t) {
        const int cur = t & 1, nxt = cur ^ 1;
        float2 xv;
        if (t + 1 < NT)
            xv = *(const float2*)(x + ((seq0 + xs_seq) * NT + (t + 1)) * ND + xd0);

#pragma unroll
        for (int m = 0; m < 4; ++m) {
            const int sq = m * 16 + l15;
            short8v xa = *(const short8v*)&Hx[cur][sq][8 * lg];

            f32x4 acc[4];
#pragma unroll
            for (int g = 0; g < 4; ++g)
                acc[g] = (f32x4){bv[g], bv[g], bv[g], bv[g]};

            if (t > 0) {
#pragma unroll
                for (int kt = 0; kt < 4; ++kt) {
                    const int kk = (kt * 32 + 8 * lg) ^ swzr;
                    short8v ah = *(const short8v*)&Hhi[cur][sq][kk];
#pragma unroll
                    for (int g = 0; g < 4; ++g)
                        acc[g] = __builtin_amdgcn_mfma_f32_16x16x32_bf16(ah, Bh[kt][g], acc[g], 0, 0, 0);
                }
            }
#pragma unroll
            for (int g = 0; g < 4; ++g)
                acc[g] = __builtin_amdgcn_mfma_f32_16x16x32_bf16(xa, b1[g], acc[g], 0, 0, 0);

#pragma unroll
            for (int r = 0; r < 4; ++r) {
                const float ui = __builtin_amdgcn_exp2f(acc[0][r]);
                const float uf = __builtin_amdgcn_exp2f(acc[1][r]);
                const float ug = __builtin_amdgcn_exp2f(acc[2][r]);
                const float uo = __builtin_amdgcn_exp2f(acc[3][r]);
                const float di = 1.f + ui, df = 1.f + uf;
                const float dg = 1.f + ug, dd = 1.f + uo;
                const float r0 = __builtin_amdgcn_rcpf(di * df);
                const float r1 = __builtin_amdgcn_rcpf(dg * dd);
                const float si = r0 * df;
                const float sf = r0 * di;
                const float tg = fmaf(2.f, r1 * dd, -1.f);
                const float so = r1 * dg;
                const float cc = fmaf(sf, c[m][r], si * tg);
                c[m][r] = cc;
                const float uc = __builtin_amdgcn_exp2f(cc * N2L2E);
                const float rc = __builtin_amdgcn_rcpf(1.f + uc);
                const float hv = fmaf(2.f, so * rc, -so);
                const int sq2 = m * 16 + 4 * lg + r;
                const int jj = (j0 + l15) ^ ((sq2 & 7) << 3);
                Hhi[nxt][sq2][jj] = bf16_rn(hv);
            }
        }

        if (t + 1 < NT) {
            unsigned int p0 = pack_split(xv.x), p1 = pack_split(xv.y);
            *(ushort2*)&Hx[nxt][xs_seq][xd0] = make_ushort2((u16)p0, (u16)p1);
            *(ushort2*)&Hx[nxt][xs_seq][16 + xd0] = make_ushort2((u16)(p0 >> 16), (u16)(p1 >> 16));
        }
        __syncthreads();
    }

    // copy-out (node-major rows n*8+b): final h in Hhi[0]
    for (int ci = tid; ci < 1024; ci += 512) {
        int s = ci >> 4, g16 = ci & 15;
        int sg = g16 ^ (s & 7);
        unsigned int sglob = (unsigned int)(seq0 + s);
        unsigned int b = sglob / NN;
        unsigned int n = sglob - b * NN;
        uint4 v = *(const uint4*)&Hhi[0][s][sg * 8];
        *(uint4*)(hhi_g + ((long)n * 8 + b) * NH + g16 * 8) = v;
    }
}

// ---------------- degree accumulation ---------------------------------------
__global__ void degacc_k(const int* __restrict__ ei, const float* __restrict__ ew,
                         float* deg, int* cnt) {
    int e = blockIdx.x * 256 + threadIdx.x;
    if (e < NE) {
        int d = ei[NE + e];
        atomicAdd(&deg[d], ew[e]);
        atomicAdd(&cnt[d], 1);
    }
}

// ---------------- scan (+ dinv) ---------------------------------------------
__global__ __launch_bounds__(1024) void scan_k(const int* __restrict__ cnt,
                                               int* __restrict__ rowp,
                                               const float* __restrict__ deg,
                                               float* __restrict__ dinv) {
    for (int idx = threadIdx.x; idx < NN; idx += 1024) {
        float d = deg[idx];
        dinv[idx] = d > 0.f ? rsqrtf(d) : 0.f;
    }
    __shared__ int sA[1024];
    __shared__ int sB[1024];
    const int tid = threadIdx.x;
    const int CH = 10;
    int base = tid * CH;
    int local[CH];
    int ssum = 0;
#pragma unroll
    for (int i = 0; i < CH; ++i) {
        int idx = base + i;
        int v = (idx < NN) ? cnt[idx] : 0;
        local[i] = v; ssum += v;
    }
    int* src = sA; int* dst = sB;
    src[tid] = ssum;
    __syncthreads();
    for (int off = 1; off < 1024; off <<= 1) {
        int v = src[tid];
        if (tid >= off) v += src[tid - off];
        dst[tid] = v;
        __syncthreads();
        int* tmp = src; src = dst; dst = tmp;
    }
    int run = src[tid] - ssum;
#pragma unroll
    for (int i = 0; i < CH; ++i) {
        int idx = base + i;
        if (idx < NN) rowp[idx] = run;
        run += local[i];
    }
    if (tid == 1023) rowp[NN] = src[1023];
}

__global__ void scatter_k(const int* __restrict__ ei, const float* __restrict__ ew,
                          const float* __restrict__ dinv, const int* __restrict__ rowp,
                          int* fill, int* __restrict__ col, float* __restrict__ val)
{
    int e = blockIdx.x * 256 + threadIdx.x;
    if (e >= NE) return;
    int srcn = ei[e], d = ei[NE + e];
    int pos = rowp[d] + atomicAdd(&fill[d], 1);
    col[pos] = srcn;
    val[pos] = dinv[srcn] * ew[e] * dinv[d];
}

// ---------- fused GCN layer v2: half-split 16B agg, then @W^T via MFMA ------
// One block per node, 256 threads. Threads 0-127 process even items (incl.
// self), 128-255 odd items; each thread loads 16B (8 channels) per item.
// LDS combine, then 16x128 padded A-tile @ W^T. LAST=1 fuses the final FC.
template<int LAST>
__global__ __launch_bounds__(256) void gcn_fused_k(const u16* __restrict__ hin,
    const int* __restrict__ rowp, const int* __restrict__ col,
    const float* __restrict__ val, const float* __restrict__ dinv,
    const float* __restrict__ bias, const u16* __restrict__ Whi,
    u16* __restrict__ hout,
    const float* __restrict__ fcw, const float* __restrict__ fcb,
    float* __restrict__ out)
{
    __shared__ __align__(16) u16 Ag[16][128];    // swizzled agg (rows 8-15 = 0)
    __shared__ __align__(16) float Tmp[128][8];  // odd-half partials (4 KB)
    __shared__ __align__(16) u16 Ou[8][128];     // bf16 output staging (!LAST)
    __shared__ float hrow[8][132];               // f32 output staging (LAST)
    __shared__ float wl[16][132];                // fc weights (LAST)
    const int n = blockIdx.x;
    const int tid = threadIdx.x;
    const int half = tid >> 7;         // wave-uniform (waves 0,1 vs 2,3)
    const int l = tid & 127;           // channel-octet owner: ch 8l..8l+7

    // zero pad rows 8..15 (128 uint4 = 2048 B)
    if (tid < 128) *(uint4*)&Ag[8 + (tid >> 4)][(tid & 15) * 8] = make_uint4(0, 0, 0, 0);
    if (LAST) {
        for (int i2 = tid; i2 < 16 * 128; i2 += 256)
            wl[i2 >> 7][i2 & 127] = fcw[i2];
    }

    // ---- aggregation: items = [self] + edges; halves take even/odd ----
    const float dn = dinv[n];
    const float sn = dn * dn;          // self-loop norm
    const int e0 = rowp[n];
    const int items = rowp[n + 1] - e0 + 1;
    f32x4 aA = (f32x4){0.f, 0.f, 0.f, 0.f};
    f32x4 aB = (f32x4){0.f, 0.f, 0.f, 0.f};
    int i = half;
    if (half == 0) {                   // item 0 = self row
        const ushort4* p = (const ushort4*)(hin + (long)n * 1024 + l * 8);
        ushort4 u0 = p[0], u1 = p[1];
        aA.x = sn * bf16f(u0.x); aA.y = sn * bf16f(u0.y);
        aA.z = sn * bf16f(u0.z); aA.w = sn * bf16f(u0.w);
        aB.x = sn * bf16f(u1.x); aB.y = sn * bf16f(u1.y);
        aB.z = sn * bf16f(u1.z); aB.w = sn * bf16f(u1.w);
        i = 2;
    }
    for (; i < items; i += 2) {        // col/val wave-uniform -> s_load
        const int src = col[e0 + i - 1];
        const float w = val[e0 + i - 1];
        const ushort4* p = (const ushort4*)(hin + (long)src * 1024 + l * 8);
        ushort4 u0 = p[0], u1 = p[1];
        aA.x = fmaf(w, bf16f(u0.x), aA.x); aA.y = fmaf(w, bf16f(u0.y), aA.y);
        aA.z = fmaf(w, bf16f(u0.z), aA.z); aA.w = fmaf(w, bf16f(u0.w), aA.w);
        aB.x = fmaf(w, bf16f(u1.x), aB.x); aB.y = fmaf(w, bf16f(u1.y), aB.y);
        aB.z = fmaf(w, bf16f(u1.z), aB.z); aB.w = fmaf(w, bf16f(u1.w), aB.w);
    }
    if (half == 1) {
        *(f32x4*)&Tmp[l][0] = aA;
        *(f32x4*)&Tmp[l][4] = aB;
    }
    __syncthreads();
    if (half == 0) {
        f32x4 tA = *(const f32x4*)&Tmp[l][0];
        f32x4 tB = *(const f32x4*)&Tmp[l][4];
        const int b = l >> 4;
        const int cc = ((l & 15) * 8) ^ ((b & 7) << 3);   // 8-granule swizzle
        ushort4 p0 = make_ushort4(bf16_rn(aA.x + tA.x), bf16_rn(aA.y + tA.y),
                                  bf16_rn(aA.z + tA.z), bf16_rn(aA.w + tA.w));
        ushort4 p1 = make_ushort4(bf16_rn(aB.x + tB.x), bf16_rn(aB.y + tB.y),
                                  bf16_rn(aB.z + tB.z), bf16_rn(aB.w + tB.w));
        *(ushort4*)&Ag[b][cc] = p0;
        *(ushort4*)&Ag[b][cc + 4] = p1;
    }
    __syncthreads();

    // ---- per-node transform: (16x128 padded A) @ W^T via MFMA ----
    const int lane = tid & 63;
    const int wid = tid >> 6;          // 0..3, each wave: 2 N-tiles
    const int l15 = lane & 15;
    const int lg = lane >> 4;
    const int swzA = (l15 & 7) << 3;
#pragma unroll
    for (int jt = 0; jt < 2; ++jt) {
        const int j0 = (wid * 2 + jt) * 16;
        f32x4 acc = (f32x4){0.f, 0.f, 0.f, 0.f};
#pragma unroll
        for (int kt = 0; kt < 4; ++kt) {
            short8v ah = *(const short8v*)&Ag[l15][(kt * 32 + 8 * lg) ^ swzA];
            short8v bh = *(const short8v*)(Whi + (j0 + l15) * NH + kt * 32 + 8 * lg);
            acc = __builtin_amdgcn_mfma_f32_16x16x32_bf16(ah, bh, acc, 0, 0, 0);
        }
        if (lg < 2) {                  // valid rows 0..7
            const float bj = bias[j0 + l15];
#pragma unroll
            for (int r = 0; r < 4; ++r) {
                const int row = 4 * lg + r;
                const float v = fmaxf(acc[r] + bj, 0.f);
                if (LAST) hrow[row][j0 + l15] = v;
                else      Ou[row][j0 + l15] = bf16_rn(v);
            }
        }
    }
    __syncthreads();

    if (LAST) {
        if (tid < 128) {
            const int b2 = tid >> 4, o = tid & 15;
            float a = fcb[o];
#pragma unroll 8
            for (int k = 0; k < NH; ++k) a = fmaf(hrow[b2][k], wl[o][k], a);
            out[((long)b2 * NN + n) * 16 + o] = a;
        }
    } else {
        if (tid < 128)                 // 2 KB contiguous copy-out
            *(uint4*)(hout + (long)n * 1024 + tid * 8) = *(const uint4*)&Ou[tid >> 4][(tid & 15) * 8];
    }
}

// ---------------------------------------------------------------------------
extern "C" void kernel_launch(void* const* d_in, const int* in_sizes, int n_in,
                              void* d_out, int out_size, void* d_ws, size_t ws_size,
                              hipStream_t stream)
{
    const float* x   = (const float*)d_in[0];
    const int*   ei  = (const int*)d_in[1];
    const float* ew  = (const float*)d_in[2];
    const float* Wih = (const float*)d_in[3];
    const float* Whh = (const float*)d_in[4];
    const float* bih = (const float*)d_in[5];
    const float* bhh = (const float*)d_in[6];
    const float* g1w = (const float*)d_in[7];
    const float* g1b = (const float*)d_in[8];
    const float* g2w = (const float*)d_in[9];
    const float* g2b = (const float*)d_in[10];
    const float* fcw = (const float*)d_in[11];
    const float* fcb = (const float*)d_in[12];
    float* out = (float*)d_out;

    char* ws = (char*)d_ws;
    u16* whh_hi  = (u16*)(ws + 0);           // 131072
    u16* wih_hi2 = (u16*)(ws + 131072);      // 32768
    u16* g1hi    = (u16*)(ws + 196608);      // 32768
    u16* g2hi    = (u16*)(ws + 229376);      // 32768
    float* deg   = (float*)(ws + 262144);
    float* dinv  = (float*)(ws + 303104);
    int*   cnt   = (int*)(ws + 344064);
    int*   fill  = (int*)(ws + 385024);
    int*   rowp  = (int*)(ws + 425984);
    int*   col   = (int*)(ws + 466176);      // 640000
    float* val   = (float*)(ws + 1106176);   // 640000
    u16* hhi     = (u16*)(ws + 2097152);     // 20480000 (node-major bf16)
    u16* h1      = (u16*)(ws + 22577152);    // 20480000 (node-major bf16)

    prep_w_k<<<256, 256, 0, stream>>>(Whh, Wih, g1w, g2w, whh_hi, wih_hi2,
                                      g1hi, g2hi, deg, cnt, fill);
    lstm4d_k<<<BN / 64, 512, 0, stream>>>(x, whh_hi, wih_hi2, bih, bhh, hhi);

    degacc_k<<<(NE + 255) / 256, 256, 0, stream>>>(ei, ew, deg, cnt);
    scan_k<<<1, 1024, 0, stream>>>(cnt, rowp, deg, dinv);
    scatter_k<<<(NE + 255) / 256, 256, 0, stream>>>(ei, ew, dinv, rowp, fill, col, val);

    gcn_fused_k<0><<<NN, 256, 0, stream>>>(hhi, rowp, col, val, dinv, g1b, g1hi,
                                           h1, nullptr, nullptr, nullptr);
    gcn_fused_k<1><<<NN, 256, 0, stream>>>(h1, rowp, col, val, dinv, g2b, g2hi,
                                           nullptr, fcw, fcb, out);
}

// Round 17
// 401.142 us; speedup vs baseline: 2.8044x; 1.0329x over previous
//
#include <hip/hip_runtime.h>
#include <math.h>

#define NB 8
#define NN 10000
#define NT 12
#define ND 16
#define NH 128
#define NE 160000
#define BN (NB * NN)  // 80000

typedef __attribute__((ext_vector_type(8))) short short8v;
typedef __attribute__((ext_vector_type(4))) float f32x4;
typedef unsigned short u16;

#define NL2E  -1.442695041f   // -log2(e)
#define N2L2E -2.885390082f   // -2*log2(e)

__device__ __forceinline__ u16 bf16_rn(float f) {
    unsigned int u = __float_as_uint(f);
    u += 0x7fffu + ((u >> 16) & 1u);
    return (u16)(u >> 16);
}
__device__ __forceinline__ float bf16f(u16 s) {
    return __uint_as_float((unsigned int)s << 16);
}
// trunc-hi + rn-lo split packed as (lo<<16)|hi  (x staging keeps hi/lo)
__device__ __forceinline__ unsigned int pack_split(float f) {
    unsigned int u = __float_as_uint(f);
    unsigned int hh = u >> 16;
    float rem = f - __uint_as_float(u & 0xffff0000u);
    unsigned int hl = bf16_rn(rem);
    return (hl << 16) | hh;
}

// ---------- prep: scaled bf16 weights (exp2 gates) + CSR init ---------------
__global__ void prep_w_k(const float* __restrict__ Whh, const float* __restrict__ Wih,
                         const float* __restrict__ g1w, const float* __restrict__ g2w,
                         u16* __restrict__ whh_hi, u16* __restrict__ wih_hi2,
                         u16* __restrict__ g1hi, u16* __restrict__ g2hi,
                         float* __restrict__ deg, int* __restrict__ cnt, int* __restrict__ fill)
{
    int i = blockIdx.x * 256 + threadIdx.x;   // 65536 threads
    if (i < 512 * 128) {
        int j = i >> 7;
        float s = ((j >> 7) == 2) ? N2L2E : NL2E;
        whh_hi[i] = bf16_rn(s * Whh[i]);
    }
    if (i < 512 * 16) {
        int row = i >> 4, d = i & 15;
        float s = ((row >> 7) == 2) ? N2L2E : NL2E;
        u16 h = bf16_rn(s * Wih[i]);
        wih_hi2[row * 32 + d] = h;        // duplicated: pairs with [x_hi; x_lo]
        wih_hi2[row * 32 + 16 + d] = h;
    }
    if (i < 128 * 128) {
        g1hi[i] = bf16_rn(g1w[i]);
        g2hi[i] = bf16_rn(g2w[i]);
    }
    if (i < NN) { deg[i] = 1.0f; cnt[i] = 0; fill[i] = 0; }   // 1.0 = self-loop
}

// ---------- LSTM v4d (round-16 proven, 244 us): native exp2 epilogue --------
__global__ __launch_bounds__(512, 2) void lstm4d_k(
    const float* __restrict__ x,
    const u16* __restrict__ whh_hi, const u16* __restrict__ wih_hi2,
    const float* __restrict__ bih, const float* __restrict__ bhh,
    u16* __restrict__ hhi_g)
{
    __shared__ __align__(16) u16 Hhi[2][64][128];   // 32 KB (double-buffered)
    __shared__ __align__(16) u16 Hx[2][64][40];     // 10 KB (80B rows)
    const int tid = threadIdx.x;
    const int lane = tid & 63;
    const int wid = tid >> 6;
    const int j0 = wid * 16;
    const int l15 = lane & 15;
    const int lg = lane >> 4;          // 0..3
    const long seq0 = (long)blockIdx.x * 64;
    const int swzr = (l15 & 7) << 3;   // read-side XOR swizzle
    const int xs_seq = tid >> 3;       // x staging: 8 threads/seq-row
    const int xd0 = (tid & 7) * 2;

    short8v Bh[4][4];                  // [kt][gate]
    short8v b1[4];
    float bv[4];
#pragma unroll
    for (int kt = 0; kt < 4; ++kt)
#pragma unroll
        for (int g = 0; g < 4; ++g) {
            int row = g * NH + j0 + l15;
            Bh[kt][g] = *(const short8v*)(whh_hi + row * NH + kt * 32 + 8 * lg);
        }
#pragma unroll
    for (int g = 0; g < 4; ++g) {
        int row = g * NH + j0 + l15;
        b1[g] = *(const short8v*)(wih_hi2 + row * 32 + 8 * lg);
        bv[g] = (bih[row] + bhh[row]) * ((g == 2) ? N2L2E : NL2E);
    }

    {
        float2 xv = *(const float2*)(x + ((seq0 + xs_seq) * NT + 0) * ND + xd0);
        unsigned int p0 = pack_split(xv.x), p1 = pack_split(xv.y);
        *(ushort2*)&Hx[0][xs_seq][xd0] = make_ushort2((u16)p0, (u16)p1);
        *(ushort2*)&Hx[0][xs_seq][16 + xd0] = make_ushort2((u16)(p0 >> 16), (u16)(p1 >> 16));
    }
    f32x4 c[4];
#pragma unroll
    for (int m = 0; m < 4; ++m) c[m] = (f32x4){0.f, 0.f, 0.f, 0.f};
    __syncthreads();

    for (int t = 0; t < NT; ++t) {
        const int cur = t & 1, nxt = cur ^ 1;
        float2 xv;
        if (t + 1 < NT)
            xv = *(const float2*)(x + ((seq0 + xs_seq) * NT + (t + 1)) * ND + xd0);

#pragma unroll
        for (int m = 0; m < 4; ++m) {
            const int sq = m * 16 + l15;
            short8v xa = *(const short8v*)&Hx[cur][sq][8 * lg];

            f32x4 acc[4];
#pragma unroll
            for (int g = 0; g < 4; ++g)
                acc[g] = (f32x4){bv[g], bv[g], bv[g], bv[g]};

            if (t > 0) {
#pragma unroll
                for (int kt = 0; kt < 4; ++kt) {
                    const int kk = (kt * 32 + 8 * lg) ^ swzr;
                    short8v ah = *(const short8v*)&Hhi[cur][sq][kk];
#pragma unroll
                    for (int g = 0; g < 4; ++g)
                        acc[g] = __builtin_amdgcn_mfma_f32_16x16x32_bf16(ah, Bh[kt][g], acc[g], 0, 0, 0);
                }
            }
#pragma unroll
            for (int g = 0; g < 4; ++g)
                acc[g] = __builtin_amdgcn_mfma_f32_16x16x32_bf16(xa, b1[g], acc[g], 0, 0, 0);

#pragma unroll
            for (int r = 0; r < 4; ++r) {
                const float ui = __builtin_amdgcn_exp2f(acc[0][r]);
                const float uf = __builtin_amdgcn_exp2f(acc[1][r]);
                const float ug = __builtin_amdgcn_exp2f(acc[2][r]);
                const float uo = __builtin_amdgcn_exp2f(acc[3][r]);
                const float di = 1.f + ui, df = 1.f + uf;
                const float dg = 1.f + ug, dd = 1.f + uo;
                const float r0 = __builtin_amdgcn_rcpf(di * df);
                const float r1 = __builtin_amdgcn_rcpf(dg * dd);
                const float si = r0 * df;
                const float sf = r0 * di;
                const float tg = fmaf(2.f, r1 * dd, -1.f);
                const float so = r1 * dg;
                const float cc = fmaf(sf, c[m][r], si * tg);
                c[m][r] = cc;
                const float uc = __builtin_amdgcn_exp2f(cc * N2L2E);
                const float rc = __builtin_amdgcn_rcpf(1.f + uc);
                const float hv = fmaf(2.f, so * rc, -so);
                const int sq2 = m * 16 + 4 * lg + r;
                const int jj = (j0 + l15) ^ ((sq2 & 7) << 3);
                Hhi[nxt][sq2][jj] = bf16_rn(hv);
            }
        }

        if (t + 1 < NT) {
            unsigned int p0 = pack_split(xv.x), p1 = pack_split(xv.y);
            *(ushort2*)&Hx[nxt][xs_seq][xd0] = make_ushort2((u16)p0, (u16)p1);
            *(ushort2*)&Hx[nxt][xs_seq][16 + xd0] = make_ushort2((u16)(p0 >> 16), (u16)(p1 >> 16));
        }
        __syncthreads();
    }

    // copy-out (node-major rows n*8+b): final h in Hhi[0]
    for (int ci = tid; ci < 1024; ci += 512) {
        int s = ci >> 4, g16 = ci & 15;
        int sg = g16 ^ (s & 7);
        unsigned int sglob = (unsigned int)(seq0 + s);
        unsigned int b = sglob / NN;
        unsigned int n = sglob - b * NN;
        uint4 v = *(const uint4*)&Hhi[0][s][sg * 8];
        *(uint4*)(hhi_g + ((long)n * 8 + b) * NH + g16 * 8) = v;
    }
}

// ---------------- degree accumulation ---------------------------------------
__global__ void degacc_k(const int* __restrict__ ei, const float* __restrict__ ew,
                         float* deg, int* cnt) {
    int e = blockIdx.x * 256 + threadIdx.x;
    if (e < NE) {
        int d = ei[NE + e];
        atomicAdd(&deg[d], ew[e]);
        atomicAdd(&cnt[d], 1);
    }
}

// ---------------- scan (+ dinv) ---------------------------------------------
__global__ __launch_bounds__(1024) void scan_k(const int* __restrict__ cnt,
                                               int* __restrict__ rowp,
                                               const float* __restrict__ deg,
                                               float* __restrict__ dinv) {
    for (int idx = threadIdx.x; idx < NN; idx += 1024) {
        float d = deg[idx];
        dinv[idx] = d > 0.f ? rsqrtf(d) : 0.f;
    }
    __shared__ int sA[1024];
    __shared__ int sB[1024];
    const int tid = threadIdx.x;
    const int CH = 10;
    int base = tid * CH;
    int local[CH];
    int ssum = 0;
#pragma unroll
    for (int i = 0; i < CH; ++i) {
        int idx = base + i;
        int v = (idx < NN) ? cnt[idx] : 0;
        local[i] = v; ssum += v;
    }
    int* src = sA; int* dst = sB;
    src[tid] = ssum;
    __syncthreads();
    for (int off = 1; off < 1024; off <<= 1) {
        int v = src[tid];
        if (tid >= off) v += src[tid - off];
        dst[tid] = v;
        __syncthreads();
        int* tmp = src; src = dst; dst = tmp;
    }
    int run = src[tid] - ssum;
#pragma unroll
    for (int i = 0; i < CH; ++i) {
        int idx = base + i;
        if (idx < NN) rowp[idx] = run;
        run += local[i];
    }
    if (tid == 1023) rowp[NN] = src[1023];
}

__global__ void scatter_k(const int* __restrict__ ei, const float* __restrict__ ew,
                          const float* __restrict__ dinv, const int* __restrict__ rowp,
                          int* fill, int* __restrict__ col, float* __restrict__ val)
{
    int e = blockIdx.x * 256 + threadIdx.x;
    if (e >= NE) return;
    int srcn = ei[e], d = ei[NE + e];
    int pos = rowp[d] + atomicAdd(&fill[d], 1);
    col[pos] = srcn;
    val[pos] = dinv[srcn] * ew[e] * dinv[d];
}

// ---------- fused GCN layer (round-15 v1): agg then @W^T via MFMA -----------
// One block per node, 256 threads. LAST=1 additionally applies the final FC.
// A-tile: agg rows 0-7 (batches), rows 8-15 zero-pad; XOR-swizzled LDS.
template<int LAST>
__global__ __launch_bounds__(256) void gcn_fused_k(const u16* __restrict__ hin,
    const int* __restrict__ rowp, const int* __restrict__ col,
    const float* __restrict__ val, const float* __restrict__ dinv,
    const float* __restrict__ bias, const u16* __restrict__ Whi,
    u16* __restrict__ hout,
    const float* __restrict__ fcw, const float* __restrict__ fcb,
    float* __restrict__ out)
{
    __shared__ __align__(16) u16 Ag[16][128];    // swizzled agg (rows 8-15 = 0)
    __shared__ __align__(16) u16 Ou[8][128];     // bf16 output staging (!LAST)
    __shared__ float hrow[8][132];               // f32 output staging (LAST)
    __shared__ float wl[16][132];                // fc weights (LAST)
    const int n = blockIdx.x;
    const int tid = threadIdx.x;
    const int b = tid >> 5;            // batch 0..7
    const int q = tid & 31;            // 4-channel slot

    // zero pad rows 8..15 (128 uint4 = 2048 B)
    if (tid < 128) *(uint4*)&Ag[8 + (tid >> 4)][(tid & 15) * 8] = make_uint4(0, 0, 0, 0);
    if (LAST) {
        for (int l = tid; l < 16 * 128; l += 256)
            wl[l >> 7][l & 127] = fcw[l];
    }

    // ---- aggregation (node-major bf16 rows, dual accumulators) ----
    const float dn = dinv[n];
    const float sn = dn * dn;
    float4 accA, accB = make_float4(0.f, 0.f, 0.f, 0.f);
    {
        ushort4 u = *(const ushort4*)(hin + (long)n * 1024 + tid * 4);
        accA.x = sn * bf16f(u.x); accA.y = sn * bf16f(u.y);
        accA.z = sn * bf16f(u.z); accA.w = sn * bf16f(u.w);
    }
    int e = rowp[n];
    const int e1 = rowp[n + 1];
    for (; e + 2 <= e1; e += 2) {
        const int s0 = col[e], s1 = col[e + 1];
        const float w0 = val[e], w1 = val[e + 1];
        const ushort4 u0 = *(const ushort4*)(hin + (long)s0 * 1024 + tid * 4);
        const ushort4 u1 = *(const ushort4*)(hin + (long)s1 * 1024 + tid * 4);
        accA.x = fmaf(w0, bf16f(u0.x), accA.x); accA.y = fmaf(w0, bf16f(u0.y), accA.y);
        accA.z = fmaf(w0, bf16f(u0.z), accA.z); accA.w = fmaf(w0, bf16f(u0.w), accA.w);
        accB.x = fmaf(w1, bf16f(u1.x), accB.x); accB.y = fmaf(w1, bf16f(u1.y), accB.y);
        accB.z = fmaf(w1, bf16f(u1.z), accB.z); accB.w = fmaf(w1, bf16f(u1.w), accB.w);
    }
    if (e < e1) {
        const int s0 = col[e];
        const float w0 = val[e];
        const ushort4 u0 = *(const ushort4*)(hin + (long)s0 * 1024 + tid * 4);
        accA.x = fmaf(w0, bf16f(u0.x), accA.x); accA.y = fmaf(w0, bf16f(u0.y), accA.y);
        accA.z = fmaf(w0, bf16f(u0.z), accA.z); accA.w = fmaf(w0, bf16f(u0.w), accA.w);
    }
    // write agg row (bf16, swizzled): elements (q*4..q*4+3) ^ ((b&7)<<3)
    {
        ushort4 a4 = make_ushort4(bf16_rn(accA.x + accB.x), bf16_rn(accA.y + accB.y),
                                  bf16_rn(accA.z + accB.z), bf16_rn(accA.w + accB.w));
        *(ushort4*)&Ag[b][(q * 4) ^ ((b & 7) << 3)] = a4;
    }
    __syncthreads();

    // ---- per-node transform: (16x128 padded A) @ W^T via MFMA ----
    const int lane = tid & 63;
    const int wid = tid >> 6;          // 0..3, each wave: 2 N-tiles
    const int l15 = lane & 15;
    const int lg = lane >> 4;
    const int swzA = (l15 & 7) << 3;
#pragma unroll
    for (int jt = 0; jt < 2; ++jt) {
        const int j0 = (wid * 2 + jt) * 16;
        f32x4 acc = (f32x4){0.f, 0.f, 0.f, 0.f};
#pragma unroll
        for (int kt = 0; kt < 4; ++kt) {
            short8v ah = *(const short8v*)&Ag[l15][(kt * 32 + 8 * lg) ^ swzA];
            short8v bh = *(const short8v*)(Whi + (j0 + l15) * NH + kt * 32 + 8 * lg);
            acc = __builtin_amdgcn_mfma_f32_16x16x32_bf16(ah, bh, acc, 0, 0, 0);
        }
        if (lg < 2) {                  // valid rows 0..7
            const float bj = bias[j0 + l15];
#pragma unroll
            for (int r = 0; r < 4; ++r) {
                const int row = 4 * lg + r;
                const float v = fmaxf(acc[r] + bj, 0.f);
                if (LAST) hrow[row][j0 + l15] = v;
                else      Ou[row][j0 + l15] = bf16_rn(v);
            }
        }
    }
    __syncthreads();

    if (LAST) {
        if (tid < 128) {
            const int b2 = tid >> 4, o = tid & 15;
            float a = fcb[o];
#pragma unroll 8
            for (int k = 0; k < NH; ++k) a = fmaf(hrow[b2][k], wl[o][k], a);
            out[((long)b2 * NN + n) * 16 + o] = a;
        }
    } else {
        if (tid < 128)                 // 2 KB contiguous copy-out
            *(uint4*)(hout + (long)n * 1024 + tid * 8) = *(const uint4*)&Ou[tid >> 4][(tid & 15) * 8];
    }
}

// ---------------------------------------------------------------------------
extern "C" void kernel_launch(void* const* d_in, const int* in_sizes, int n_in,
                              void* d_out, int out_size, void* d_ws, size_t ws_size,
                              hipStream_t stream)
{
    const float* x   = (const float*)d_in[0];
    const int*   ei  = (const int*)d_in[1];
    const float* ew  = (const float*)d_in[2];
    const float* Wih = (const float*)d_in[3];
    const float* Whh = (const float*)d_in[4];
    const float* bih = (const float*)d_in[5];
    const float* bhh = (const float*)d_in[6];
    const float* g1w = (const float*)d_in[7];
    const float* g1b = (const float*)d_in[8];
    const float* g2w = (const float*)d_in[9];
    const float* g2b = (const float*)d_in[10];
    const float* fcw = (const float*)d_in[11];
    const float* fcb = (const float*)d_in[12];
    float* out = (float*)d_out;

    char* ws = (char*)d_ws;
    u16* whh_hi  = (u16*)(ws + 0);           // 131072
    u16* wih_hi2 = (u16*)(ws + 131072);      // 32768
    u16* g1hi    = (u16*)(ws + 196608);      // 32768
    u16* g2hi    = (u16*)(ws + 229376);      // 32768
    float* deg   = (float*)(ws + 262144);
    float* dinv  = (float*)(ws + 303104);
    int*   cnt   = (int*)(ws + 344064);
    int*   fill  = (int*)(ws + 385024);
    int*   rowp  = (int*)(ws + 425984);
    int*   col   = (int*)(ws + 466176);      // 640000
    float* val   = (float*)(ws + 1106176);   // 640000
    u16* hhi     = (u16*)(ws + 2097152);     // 20480000 (node-major bf16)
    u16* h1      = (u16*)(ws + 22577152);    // 20480000 (node-major bf16)

    prep_w_k<<<256, 256, 0, stream>>>(Whh, Wih, g1w, g2w, whh_hi, wih_hi2,
                                      g1hi, g2hi, deg, cnt, fill);
    lstm4d_k<<<BN / 64, 512, 0, stream>>>(x, whh_hi, wih_hi2, bih, bhh, hhi);

    degacc_k<<<(NE + 255) / 256, 256, 0, stream>>>(ei, ew, deg, cnt);
    scan_k<<<1, 1024, 0, stream>>>(cnt, rowp, deg, dinv);
    scatter_k<<<(NE + 255) / 256, 256, 0, stream>>>(ei, ew, dinv, rowp, fill, col, val);

    gcn_fused_k<0><<<NN, 256, 0, stream>>>(hhi, rowp, col, val, dinv, g1b, g1hi,
                                           h1, nullptr, nullptr, nullptr);
    gcn_fused_k<1><<<NN, 256, 0, stream>>>(h1, rowp, col, val, dinv, g2b, g2hi,
                                           nullptr, fcw, fcb, out);
}